// Round 1
// baseline (5181.341 us; speedup 1.0000x reference)
//
#include <hip/hip_runtime.h>
#include <math.h>

static constexpr int Bb = 2, Ss = 2048, Dd = 1024, Hh = 16, DHh = 64;

// ---- GEMM: C = A(MxK) @ W(KxN) + bias, fp32 ----
// scatter=0: C row-major (M x N).
// scatter=1: write to (B,H,S,DH): row=b*S+s, col=h*DH+d -> out[((b*H+h)*S+s)*DH+d]
__global__ __launch_bounds__(256)
void gemm_bias_kernel(const float* __restrict__ A, const float* __restrict__ W,
                      const float* __restrict__ bias, float* __restrict__ C,
                      int M, int N, int K, int scatter)
{
    __shared__ float As[16][65];   // [k][m]
    __shared__ float Bs[16][65];   // [k][n]
    const int tid = threadIdx.x;
    const int tx = tid & 15, ty = tid >> 4;
    const int row0 = blockIdx.y * 64, col0 = blockIdx.x * 64;

    float acc[4][4] = {};

    for (int k0 = 0; k0 < K; k0 += 16) {
        // load A tile 64x16 (row-major A)
        for (int i = tid; i < 64 * 16; i += 256) {
            int m = i >> 4, k = i & 15;
            As[k][m] = A[(size_t)(row0 + m) * K + k0 + k];
        }
        // load W tile 16x64
        for (int i = tid; i < 16 * 64; i += 256) {
            int k = i >> 6, n = i & 63;
            Bs[k][n] = W[(size_t)(k0 + k) * N + col0 + n];
        }
        __syncthreads();
#pragma unroll
        for (int k = 0; k < 16; ++k) {
            float a[4], w[4];
#pragma unroll
            for (int i = 0; i < 4; ++i) a[i] = As[k][ty * 4 + i];
#pragma unroll
            for (int j = 0; j < 4; ++j) w[j] = Bs[k][tx * 4 + j];
#pragma unroll
            for (int i = 0; i < 4; ++i)
#pragma unroll
                for (int j = 0; j < 4; ++j)
                    acc[i][j] = fmaf(a[i], w[j], acc[i][j]);
        }
        __syncthreads();
    }

#pragma unroll
    for (int i = 0; i < 4; ++i) {
        int row = row0 + ty * 4 + i;
#pragma unroll
        for (int j = 0; j < 4; ++j) {
            int col = col0 + tx * 4 + j;
            float v = acc[i][j] + bias[col];
            if (scatter) {
                int b_ = row / Ss, s_ = row % Ss;
                int h_ = col / DHh, d_ = col & (DHh - 1);
                C[(((size_t)(b_ * Hh + h_)) * Ss + s_) * DHh + d_] = v;
            } else {
                C[(size_t)row * N + col] = v;
            }
        }
    }
}

// ---- Attention: one 64-lane wave per query row, flash-style over valid keys ----
// Q,K,V: (B,H,S,DH) fp32.  O: (B,S,D) fp32.
__global__ __launch_bounds__(64)
void attn_kernel(const float* __restrict__ Q, const float* __restrict__ K,
                 const float* __restrict__ V, const int* __restrict__ valid_nums,
                 float* __restrict__ O)
{
    const int idx = blockIdx.x;             // b*H*S + h*S + q
    const int qi = idx % Ss;
    const int h  = (idx / Ss) % Hh;
    const int b  = idx / (Ss * Hh);
    const int lane = threadIdx.x;
    const int nv = valid_nums[b];           // >= 1

    const float* Qr = Q + (((size_t)(b * Hh + h)) * Ss + qi) * DHh;
    const float* Kb = K + ((size_t)(b * Hh + h)) * Ss * DHh;
    const float* Vb = V + ((size_t)(b * Hh + h)) * Ss * DHh;

    __shared__ float qs[DHh];
    __shared__ float os[64][65];

    qs[lane] = Qr[lane];
    __syncthreads();

    float o[DHh];
#pragma unroll
    for (int d = 0; d < DHh; ++d) o[d] = 0.f;
    float m = -INFINITY, l = 0.f;
    const float sc = 0.125f;                // 1/sqrt(64)

    for (int j = lane; j < nv; j += 64) {
        const float* Kr = Kb + (size_t)j * DHh;
        float s = 0.f;
#pragma unroll
        for (int d = 0; d < DHh; d += 4) {
            float4 k4 = *(const float4*)(Kr + d);
            s = fmaf(qs[d],     k4.x, s);
            s = fmaf(qs[d + 1], k4.y, s);
            s = fmaf(qs[d + 2], k4.z, s);
            s = fmaf(qs[d + 3], k4.w, s);
        }
        s *= sc;
        float mn = fmaxf(m, s);
        float corr = __expf(m - mn);        // m=-inf -> corr=0
        float p = __expf(s - mn);
        l = l * corr + p;
        const float* Vr = Vb + (size_t)j * DHh;
#pragma unroll
        for (int d = 0; d < DHh; d += 4) {
            float4 v4 = *(const float4*)(Vr + d);
            o[d]     = fmaf(o[d],     corr, p * v4.x);
            o[d + 1] = fmaf(o[d + 1], corr, p * v4.y);
            o[d + 2] = fmaf(o[d + 2], corr, p * v4.z);
            o[d + 3] = fmaf(o[d + 3], corr, p * v4.w);
        }
        m = mn;
    }

    // combine across 64 lanes
    float gm = m;
#pragma unroll
    for (int off = 32; off; off >>= 1) gm = fmaxf(gm, __shfl_xor(gm, off));
    float scale = (l > 0.f) ? __expf(m - gm) : 0.f;
    float gl = l * scale;
#pragma unroll
    for (int off = 32; off; off >>= 1) gl += __shfl_xor(gl, off);

#pragma unroll
    for (int d = 0; d < DHh; ++d) os[lane][d] = o[d] * scale;
    __syncthreads();

    float od = 0.f;
#pragma unroll
    for (int ln = 0; ln < 64; ++ln) od += os[ln][lane];
    od /= gl;

    O[((size_t)b * Ss + qi) * Dd + h * DHh + lane] = od;
}

extern "C" void kernel_launch(void* const* d_in, const int* in_sizes, int n_in,
                              void* d_out, int out_size, void* d_ws, size_t ws_size,
                              hipStream_t stream) {
    const float* x     = (const float*)d_in[0];
    const int*   valid = (const int*)d_in[1];
    const float* Wq = (const float*)d_in[2];
    const float* bq = (const float*)d_in[3];
    const float* Wk = (const float*)d_in[4];
    const float* bk = (const float*)d_in[5];
    const float* Wv = (const float*)d_in[6];
    const float* bv = (const float*)d_in[7];
    const float* Wo = (const float*)d_in[8];
    const float* bo = (const float*)d_in[9];

    const size_t per = (size_t)Bb * Hh * Ss * DHh;   // 4,194,304 floats
    float* Q = (float*)d_ws;
    float* K = Q + per;
    float* V = K + per;
    float* O = V + per;                               // (B,S,D) — total 64 MB

    dim3 ggrid(Dd / 64, (Bb * Ss) / 64);
    gemm_bias_kernel<<<ggrid, 256, 0, stream>>>(x, Wq, bq, Q, Bb * Ss, Dd, Dd, 1);
    gemm_bias_kernel<<<ggrid, 256, 0, stream>>>(x, Wk, bk, K, Bb * Ss, Dd, Dd, 1);
    gemm_bias_kernel<<<ggrid, 256, 0, stream>>>(x, Wv, bv, V, Bb * Ss, Dd, Dd, 1);

    attn_kernel<<<Bb * Hh * Ss, 64, 0, stream>>>(Q, K, V, valid, O);

    gemm_bias_kernel<<<ggrid, 256, 0, stream>>>(O, Wo, bo, (float*)d_out,
                                                Bb * Ss, Dd, Dd, 0);
}

// Round 2
// 909.722 us; speedup vs baseline: 5.6955x; 5.6955x over previous
//
#include <hip/hip_runtime.h>
#include <hip/hip_bf16.h>
#include <math.h>

static constexpr int Bb = 2, Ss = 2048, Dd = 1024, Hh = 16, DHh = 64;

typedef __attribute__((ext_vector_type(8))) short bf16x8;
typedef __attribute__((ext_vector_type(4))) float f32x4;

__device__ inline short f2b(float f) {
    __hip_bfloat16 h = __float2bfloat16(f);
    return *reinterpret_cast<short*>(&h);
}

// ---- GEMM: C = A(MxK) @ W(KxN) + bias, fp32 (unchanged from R1) ----
__global__ __launch_bounds__(256)
void gemm_bias_kernel(const float* __restrict__ A, const float* __restrict__ W,
                      const float* __restrict__ bias, float* __restrict__ C,
                      int M, int N, int K, int scatter)
{
    __shared__ float As[16][65];
    __shared__ float Bs[16][65];
    const int tid = threadIdx.x;
    const int tx = tid & 15, ty = tid >> 4;
    const int row0 = blockIdx.y * 64, col0 = blockIdx.x * 64;

    float acc[4][4] = {};

    for (int k0 = 0; k0 < K; k0 += 16) {
        for (int i = tid; i < 64 * 16; i += 256) {
            int m = i >> 4, k = i & 15;
            As[k][m] = A[(size_t)(row0 + m) * K + k0 + k];
        }
        for (int i = tid; i < 16 * 64; i += 256) {
            int k = i >> 6, n = i & 63;
            Bs[k][n] = W[(size_t)(k0 + k) * N + col0 + n];
        }
        __syncthreads();
#pragma unroll
        for (int k = 0; k < 16; ++k) {
            float a[4], w[4];
#pragma unroll
            for (int i = 0; i < 4; ++i) a[i] = As[k][ty * 4 + i];
#pragma unroll
            for (int j = 0; j < 4; ++j) w[j] = Bs[k][tx * 4 + j];
#pragma unroll
            for (int i = 0; i < 4; ++i)
#pragma unroll
                for (int j = 0; j < 4; ++j)
                    acc[i][j] = fmaf(a[i], w[j], acc[i][j]);
        }
        __syncthreads();
    }

#pragma unroll
    for (int i = 0; i < 4; ++i) {
        int row = row0 + ty * 4 + i;
#pragma unroll
        for (int j = 0; j < 4; ++j) {
            int col = col0 + tx * 4 + j;
            float v = acc[i][j] + bias[col];
            if (scatter) {
                int b_ = row / Ss, s_ = row % Ss;
                int h_ = col / DHh, d_ = col & (DHh - 1);
                C[(((size_t)(b_ * Hh + h_)) * Ss + s_) * DHh + d_] = v;
            } else {
                C[(size_t)row * N + col] = v;
            }
        }
    }
}

// ---- Flash attention, bf16 MFMA 16x16x32, fp32 softmax/accum ----
// Q,K,V: (B,H,S,DH) fp32 in ws.  O: (B,S,D) fp32.
// Block: 64 queries of one (b,h). 4 waves, each owns 16 query rows.
__global__ __launch_bounds__(256)
void attn_mfma_kernel(const float* __restrict__ Q, const float* __restrict__ K,
                      const float* __restrict__ V, const int* __restrict__ valid_nums,
                      float* __restrict__ O)
{
    const int bh = blockIdx.y;            // b*H + h
    const int b  = bh / Hh, h = bh % Hh;
    const int q0 = blockIdx.x * 64;
    const int tid  = threadIdx.x;
    const int wave = tid >> 6;
    const int lane = tid & 63;
    const int lg = lane >> 4;             // lane group 0..3
    const int ll = lane & 15;

    const int nv = valid_nums[b];         // >= 1
    const int ntiles = (nv + 63) >> 6;

    const float* Qb = Q + (size_t)bh * Ss * DHh;
    const float* Kb = K + (size_t)bh * Ss * DHh;
    const float* Vb = V + (size_t)bh * Ss * DHh;

    __shared__ unsigned short Ks[64][72];     // [key][dim], +8 pad
    __shared__ unsigned short Vt[64][72];     // [dim][key], +8 pad
    __shared__ unsigned short Ps[4][16][72];  // per-wave P tile [row][key]

    // Q A-fragments: row = ll, k-dim = ks*32 + lg*8 + j
    bf16x8 qa[2];
    {
        const float* qrow = Qb + (size_t)(q0 + wave * 16 + ll) * DHh;
#pragma unroll
        for (int ks = 0; ks < 2; ++ks) {
            const float4* q4 = (const float4*)(qrow + ks * 32 + lg * 8);
            float4 a = q4[0], c = q4[1];
            bf16x8 t;
            t[0] = f2b(a.x); t[1] = f2b(a.y); t[2] = f2b(a.z); t[3] = f2b(a.w);
            t[4] = f2b(c.x); t[5] = f2b(c.y); t[6] = f2b(c.z); t[7] = f2b(c.w);
            qa[ks] = t;
        }
    }

    f32x4 o[4];
#pragma unroll
    for (int nt = 0; nt < 4; ++nt) { o[nt][0]=0.f; o[nt][1]=0.f; o[nt][2]=0.f; o[nt][3]=0.f; }
    float m[4], lsum[4];
#pragma unroll
    for (int r = 0; r < 4; ++r) { m[r] = -INFINITY; lsum[r] = 0.f; }

    const int key_stage = tid >> 2;           // 0..63
    const int d0_stage  = (tid & 3) * 16;     // 0,16,32,48
    const float sc = 0.125f;                  // 1/sqrt(64)

    for (int kt = 0; kt < ntiles; ++kt) {
        const int k0 = kt * 64;
        __syncthreads();   // previous tile fully consumed
        // stage K (natural) and V (transposed) as bf16
        {
            const float4* sk = (const float4*)(Kb + (size_t)(k0 + key_stage) * DHh + d0_stage);
            const float4* sv = (const float4*)(Vb + (size_t)(k0 + key_stage) * DHh + d0_stage);
#pragma unroll
            for (int jj = 0; jj < 2; ++jj) {
                float4 a = sk[2 * jj], c = sk[2 * jj + 1];
                bf16x8 t;
                t[0] = f2b(a.x); t[1] = f2b(a.y); t[2] = f2b(a.z); t[3] = f2b(a.w);
                t[4] = f2b(c.x); t[5] = f2b(c.y); t[6] = f2b(c.z); t[7] = f2b(c.w);
                *(bf16x8*)&Ks[key_stage][d0_stage + jj * 8] = t;
            }
#pragma unroll
            for (int jj = 0; jj < 4; ++jj) {
                float4 a = sv[jj];
                int dd = d0_stage + jj * 4;
                Vt[dd + 0][key_stage] = (unsigned short)f2b(a.x);
                Vt[dd + 1][key_stage] = (unsigned short)f2b(a.y);
                Vt[dd + 2][key_stage] = (unsigned short)f2b(a.z);
                Vt[dd + 3][key_stage] = (unsigned short)f2b(a.w);
            }
        }
        __syncthreads();

        // S = Q K^T  (per wave: 16 rows x 64 keys)
        f32x4 s[4];
#pragma unroll
        for (int nt = 0; nt < 4; ++nt) { s[nt][0]=0.f; s[nt][1]=0.f; s[nt][2]=0.f; s[nt][3]=0.f; }
#pragma unroll
        for (int ks = 0; ks < 2; ++ks) {
#pragma unroll
            for (int nt = 0; nt < 4; ++nt) {
                bf16x8 kb = *(const bf16x8*)&Ks[nt * 16 + ll][ks * 32 + lg * 8];
                s[nt] = __builtin_amdgcn_mfma_f32_16x16x32_bf16(qa[ks], kb, s[nt], 0, 0, 0);
            }
        }

        // scale + mask + online softmax (row r lives at row=(lg*4+r), col=ll per nt)
        float p[4][4];   // [nt][r]
        float corr[4];
#pragma unroll
        for (int r = 0; r < 4; ++r) {
            float mx = -INFINITY;
#pragma unroll
            for (int nt = 0; nt < 4; ++nt) {
                float svv = s[nt][r] * sc;
                int key = k0 + nt * 16 + ll;
                svv = (key < nv) ? svv : -INFINITY;
                p[nt][r] = svv;
                mx = fmaxf(mx, svv);
            }
            mx = fmaxf(mx, __shfl_xor(mx, 1));
            mx = fmaxf(mx, __shfl_xor(mx, 2));
            mx = fmaxf(mx, __shfl_xor(mx, 4));
            mx = fmaxf(mx, __shfl_xor(mx, 8));
            float mn = fmaxf(m[r], mx);
            corr[r] = __expf(m[r] - mn);      // m=-inf -> 0
            m[r] = mn;
            float ps = 0.f;
#pragma unroll
            for (int nt = 0; nt < 4; ++nt) {
                float pv = __expf(p[nt][r] - mn);
                p[nt][r] = pv;
                ps += pv;
            }
            ps += __shfl_xor(ps, 1);
            ps += __shfl_xor(ps, 2);
            ps += __shfl_xor(ps, 4);
            ps += __shfl_xor(ps, 8);
            lsum[r] = lsum[r] * corr[r] + ps;
        }

        // P -> per-wave LDS (row = lg*4+r, col = nt*16+ll), rescale O
#pragma unroll
        for (int r = 0; r < 4; ++r)
#pragma unroll
            for (int nt = 0; nt < 4; ++nt)
                Ps[wave][lg * 4 + r][nt * 16 + ll] = (unsigned short)f2b(p[nt][r]);
#pragma unroll
        for (int nt = 0; nt < 4; ++nt)
#pragma unroll
            for (int r = 0; r < 4; ++r)
                o[nt][r] *= corr[r];

        // O += P V   (A=P from LDS in A-frag layout, B=V from transposed tile)
#pragma unroll
        for (int ks = 0; ks < 2; ++ks) {
            bf16x8 pa = *(const bf16x8*)&Ps[wave][ll][ks * 32 + lg * 8];
#pragma unroll
            for (int nt = 0; nt < 4; ++nt) {
                bf16x8 vb = *(const bf16x8*)&Vt[nt * 16 + ll][ks * 32 + lg * 8];
                o[nt] = __builtin_amdgcn_mfma_f32_16x16x32_bf16(pa, vb, o[nt], 0, 0, 0);
            }
        }
    }

    // epilogue: O[b][q][h*64 + dim] = o / l
#pragma unroll
    for (int r = 0; r < 4; ++r) {
        int row = q0 + wave * 16 + lg * 4 + r;
        float inv = 1.f / lsum[r];
#pragma unroll
        for (int nt = 0; nt < 4; ++nt)
            O[((size_t)b * Ss + row) * Dd + h * DHh + nt * 16 + ll] = o[nt][r] * inv;
    }
}

extern "C" void kernel_launch(void* const* d_in, const int* in_sizes, int n_in,
                              void* d_out, int out_size, void* d_ws, size_t ws_size,
                              hipStream_t stream) {
    const float* x     = (const float*)d_in[0];
    const int*   valid = (const int*)d_in[1];
    const float* Wq = (const float*)d_in[2];
    const float* bq = (const float*)d_in[3];
    const float* Wk = (const float*)d_in[4];
    const float* bk = (const float*)d_in[5];
    const float* Wv = (const float*)d_in[6];
    const float* bv = (const float*)d_in[7];
    const float* Wo = (const float*)d_in[8];
    const float* bo = (const float*)d_in[9];

    const size_t per = (size_t)Bb * Hh * Ss * DHh;   // 4,194,304 floats
    float* Q = (float*)d_ws;
    float* K = Q + per;
    float* V = K + per;
    float* O = V + per;                               // (B,S,D)

    dim3 ggrid(Dd / 64, (Bb * Ss) / 64);
    gemm_bias_kernel<<<ggrid, 256, 0, stream>>>(x, Wq, bq, Q, Bb * Ss, Dd, Dd, 1);
    gemm_bias_kernel<<<ggrid, 256, 0, stream>>>(x, Wk, bk, K, Bb * Ss, Dd, Dd, 1);
    gemm_bias_kernel<<<ggrid, 256, 0, stream>>>(x, Wv, bv, V, Bb * Ss, Dd, Dd, 1);

    dim3 agrid(Ss / 64, Bb * Hh);
    attn_mfma_kernel<<<agrid, 256, 0, stream>>>(Q, K, V, valid, O);

    gemm_bias_kernel<<<ggrid, 256, 0, stream>>>(O, Wo, bo, (float*)d_out,
                                                Bb * Ss, Dd, Dd, 0);
}

// Round 3
// 217.403 us; speedup vs baseline: 23.8329x; 4.1845x over previous
//
#include <hip/hip_runtime.h>
#include <hip/hip_bf16.h>
#include <math.h>

static constexpr int Bb = 2, Ss = 2048, Dd = 1024, Hh = 16, DHh = 64;
static constexpr int Mm = Bb * Ss;     // 4096
static constexpr int Kk = Dd;          // 1024

typedef __attribute__((ext_vector_type(8))) short bf16x8;
typedef __attribute__((ext_vector_type(4))) float f32x4;
typedef unsigned short us;

__device__ inline short f2b(float f) {
    __hip_bfloat16 h = __float2bfloat16(f);
    return *reinterpret_cast<short*>(&h);
}
__device__ inline float b2f(us u) {
    __hip_bfloat16 h = *reinterpret_cast<__hip_bfloat16*>(&u);
    return __bfloat162float(h);
}

// ---- transpose + bf16 convert: Wt[n][k] = bf16(W[k][n]); optional hi/lo split ----
__global__ __launch_bounds__(256)
void wtrans_kernel(const float* __restrict__ W, us* __restrict__ Wth,
                   us* __restrict__ Wtl, int split)
{
    __shared__ float T[64][65];
    const int n0 = blockIdx.x * 64, k0 = blockIdx.y * 64;
    const int tid = threadIdx.x;
    const int r = tid >> 2, c0 = (tid & 3) * 16;
#pragma unroll
    for (int j = 0; j < 4; ++j) {
        float4 v = *(const float4*)(W + (size_t)(k0 + r) * Dd + n0 + c0 + 4 * j);
        T[r][c0 + 4 * j + 0] = v.x;
        T[r][c0 + 4 * j + 1] = v.y;
        T[r][c0 + 4 * j + 2] = v.z;
        T[r][c0 + 4 * j + 3] = v.w;
    }
    __syncthreads();
    us hi[16], lo[16];
#pragma unroll
    for (int j = 0; j < 16; ++j) {
        float v = T[c0 + j][r];
        us h = (us)f2b(v);
        hi[j] = h;
        if (split) lo[j] = (us)f2b(v - b2f(h));
    }
    *(bf16x8*)&Wth[(size_t)(n0 + r) * Kk + k0 + c0]     = *(bf16x8*)&hi[0];
    *(bf16x8*)&Wth[(size_t)(n0 + r) * Kk + k0 + c0 + 8] = *(bf16x8*)&hi[8];
    if (split) {
        *(bf16x8*)&Wtl[(size_t)(n0 + r) * Kk + k0 + c0]     = *(bf16x8*)&lo[0];
        *(bf16x8*)&Wtl[(size_t)(n0 + r) * Kk + k0 + c0 + 8] = *(bf16x8*)&lo[8];
    }
}

// ---- fused QKV projection: bf16 MFMA, A=x fp32 (converted in staging), B=Wt bf16 ----
// out scatter to (B,H,S,DH) bf16; z selects {Q,K,V}.
__global__ __launch_bounds__(256)
void gemm_qkv_kernel(const float* __restrict__ x, const us* __restrict__ Wt,
                     const float* __restrict__ bq, const float* __restrict__ bk,
                     const float* __restrict__ bv, us* __restrict__ QKV)
{
    const int z = blockIdx.z;
    const int col0 = blockIdx.x * 128, row0 = blockIdx.y * 128;
    const int tid = threadIdx.x;
    const int wave = tid >> 6, lane = tid & 63;
    const int wr = wave >> 1, wc = wave & 1;
    const int lg = lane >> 4, ll = lane & 15;

    const float* bias = (z == 0) ? bq : (z == 1) ? bk : bv;
    const us* Wz = Wt + (size_t)z * Dd * Kk;
    us* outz = QKV + (size_t)z * Mm * Dd;

    __shared__ us As[128][40];
    __shared__ us Bs[128][40];

    f32x4 acc[4][4];
#pragma unroll
    for (int mt = 0; mt < 4; ++mt)
#pragma unroll
        for (int nt = 0; nt < 4; ++nt)
#pragma unroll
            for (int r = 0; r < 4; ++r) acc[mt][nt][r] = 0.f;

    const int ar = tid >> 2, ac = (tid & 3) * 8;

    for (int k0 = 0; k0 < Kk; k0 += 32) {
        __syncthreads();
#pragma unroll
        for (int i = 0; i < 2; ++i) {
            const int rw = ar + 64 * i;
            const float4* s4 = (const float4*)(x + (size_t)(row0 + rw) * Kk + k0 + ac);
            float4 a = s4[0], b = s4[1];
            bf16x8 t;
            t[0] = f2b(a.x); t[1] = f2b(a.y); t[2] = f2b(a.z); t[3] = f2b(a.w);
            t[4] = f2b(b.x); t[5] = f2b(b.y); t[6] = f2b(b.z); t[7] = f2b(b.w);
            *(bf16x8*)&As[rw][ac] = t;
            *(bf16x8*)&Bs[rw][ac] = *(const bf16x8*)(Wz + (size_t)(col0 + rw) * Kk + k0 + ac);
        }
        __syncthreads();

        bf16x8 af[4], bfr[4];
#pragma unroll
        for (int mt = 0; mt < 4; ++mt) af[mt]  = *(const bf16x8*)&As[wr * 64 + mt * 16 + ll][lg * 8];
#pragma unroll
        for (int nt = 0; nt < 4; ++nt) bfr[nt] = *(const bf16x8*)&Bs[wc * 64 + nt * 16 + ll][lg * 8];
#pragma unroll
        for (int mt = 0; mt < 4; ++mt)
#pragma unroll
            for (int nt = 0; nt < 4; ++nt)
                acc[mt][nt] = __builtin_amdgcn_mfma_f32_16x16x32_bf16(af[mt], bfr[nt], acc[mt][nt], 0, 0, 0);
    }

#pragma unroll
    for (int mt = 0; mt < 4; ++mt)
#pragma unroll
        for (int nt = 0; nt < 4; ++nt)
#pragma unroll
            for (int r = 0; r < 4; ++r) {
                int row = row0 + wr * 64 + mt * 16 + lg * 4 + r;
                int col = col0 + wc * 64 + nt * 16 + ll;
                float v = acc[mt][nt][r] + bias[col];
                int b_ = row >> 11, s_ = row & 2047, h_ = col >> 6, d_ = col & 63;
                outz[(((size_t)(b_ * Hh + h_)) * Ss + s_) * DHh + d_] = (us)f2b(v);
            }
}

// ---- final GEMM, split-bf16: out = (Oh+Ol) @ (Wh+Wl) + bo, fp32 out ----
__global__ __launch_bounds__(256)
void gemm_final_kernel(const us* __restrict__ Oh, const us* __restrict__ Ol,
                       const us* __restrict__ Wth, const us* __restrict__ Wtl,
                       const float* __restrict__ bo, float* __restrict__ out)
{
    const int col0 = blockIdx.x * 128, row0 = blockIdx.y * 128;
    const int tid = threadIdx.x;
    const int wave = tid >> 6, lane = tid & 63;
    const int wr = wave >> 1, wc = wave & 1;
    const int lg = lane >> 4, ll = lane & 15;

    __shared__ us Ahs[128][40];
    __shared__ us Als[128][40];
    __shared__ us Bhs[128][40];
    __shared__ us Bls[128][40];

    f32x4 acc[4][4];
#pragma unroll
    for (int mt = 0; mt < 4; ++mt)
#pragma unroll
        for (int nt = 0; nt < 4; ++nt)
#pragma unroll
            for (int r = 0; r < 4; ++r) acc[mt][nt][r] = 0.f;

    const int ar = tid >> 2, ac = (tid & 3) * 8;

    for (int k0 = 0; k0 < Kk; k0 += 32) {
        __syncthreads();
#pragma unroll
        for (int i = 0; i < 2; ++i) {
            const int rw = ar + 64 * i;
            *(bf16x8*)&Ahs[rw][ac] = *(const bf16x8*)(Oh  + (size_t)(row0 + rw) * Kk + k0 + ac);
            *(bf16x8*)&Als[rw][ac] = *(const bf16x8*)(Ol  + (size_t)(row0 + rw) * Kk + k0 + ac);
            *(bf16x8*)&Bhs[rw][ac] = *(const bf16x8*)(Wth + (size_t)(col0 + rw) * Kk + k0 + ac);
            *(bf16x8*)&Bls[rw][ac] = *(const bf16x8*)(Wtl + (size_t)(col0 + rw) * Kk + k0 + ac);
        }
        __syncthreads();

        bf16x8 ah[4], al[4], bh[4], bl[4];
#pragma unroll
        for (int mt = 0; mt < 4; ++mt) {
            ah[mt] = *(const bf16x8*)&Ahs[wr * 64 + mt * 16 + ll][lg * 8];
            al[mt] = *(const bf16x8*)&Als[wr * 64 + mt * 16 + ll][lg * 8];
        }
#pragma unroll
        for (int nt = 0; nt < 4; ++nt) {
            bh[nt] = *(const bf16x8*)&Bhs[wc * 64 + nt * 16 + ll][lg * 8];
            bl[nt] = *(const bf16x8*)&Bls[wc * 64 + nt * 16 + ll][lg * 8];
        }
#pragma unroll
        for (int mt = 0; mt < 4; ++mt)
#pragma unroll
            for (int nt = 0; nt < 4; ++nt) {
                acc[mt][nt] = __builtin_amdgcn_mfma_f32_16x16x32_bf16(ah[mt], bh[nt], acc[mt][nt], 0, 0, 0);
                acc[mt][nt] = __builtin_amdgcn_mfma_f32_16x16x32_bf16(al[mt], bh[nt], acc[mt][nt], 0, 0, 0);
                acc[mt][nt] = __builtin_amdgcn_mfma_f32_16x16x32_bf16(ah[mt], bl[nt], acc[mt][nt], 0, 0, 0);
            }
    }

#pragma unroll
    for (int mt = 0; mt < 4; ++mt)
#pragma unroll
        for (int nt = 0; nt < 4; ++nt)
#pragma unroll
            for (int r = 0; r < 4; ++r) {
                int row = row0 + wr * 64 + mt * 16 + lg * 4 + r;
                int col = col0 + wc * 64 + nt * 16 + ll;
                out[(size_t)row * Dd + col] = acc[mt][nt][r] + bo[col];
            }
}

// ---- Flash attention, bf16 in, hi/lo bf16 out ----
__global__ __launch_bounds__(256)
void attn_mfma_kernel(const us* __restrict__ Q, const us* __restrict__ K,
                      const us* __restrict__ V, const int* __restrict__ valid_nums,
                      us* __restrict__ Oh, us* __restrict__ Ol)
{
    const int bh = blockIdx.y;
    const int b  = bh / Hh, h = bh % Hh;
    const int q0 = blockIdx.x * 64;
    const int tid  = threadIdx.x;
    const int wave = tid >> 6;
    const int lane = tid & 63;
    const int lg = lane >> 4;
    const int ll = lane & 15;

    const int nv = valid_nums[b];
    const int ntiles = (nv + 63) >> 6;

    const us* Qb = Q + (size_t)bh * Ss * DHh;
    const us* Kb = K + (size_t)bh * Ss * DHh;
    const us* Vb = V + (size_t)bh * Ss * DHh;

    __shared__ us Ks[64][72];
    __shared__ us Vt[64][72];
    __shared__ us Ps[4][16][72];

    bf16x8 qa[2];
    {
        const us* qrow = Qb + (size_t)(q0 + wave * 16 + ll) * DHh;
#pragma unroll
        for (int ks = 0; ks < 2; ++ks)
            qa[ks] = *(const bf16x8*)(qrow + ks * 32 + lg * 8);
    }

    f32x4 o[4];
#pragma unroll
    for (int nt = 0; nt < 4; ++nt) { o[nt][0]=0.f; o[nt][1]=0.f; o[nt][2]=0.f; o[nt][3]=0.f; }
    float m[4], lsum[4];
#pragma unroll
    for (int r = 0; r < 4; ++r) { m[r] = -INFINITY; lsum[r] = 0.f; }

    const int key_stage = tid >> 2;
    const int d0_stage  = (tid & 3) * 16;
    const float sc = 0.125f;

    for (int kt = 0; kt < ntiles; ++kt) {
        const int k0 = kt * 64;
        __syncthreads();
        {
            const us* Kr = Kb + (size_t)(k0 + key_stage) * DHh + d0_stage;
            const us* Vr = Vb + (size_t)(k0 + key_stage) * DHh + d0_stage;
            *(bf16x8*)&Ks[key_stage][d0_stage]     = *(const bf16x8*)Kr;
            *(bf16x8*)&Ks[key_stage][d0_stage + 8] = *(const bf16x8*)(Kr + 8);
            bf16x8 v0 = *(const bf16x8*)Vr;
            bf16x8 v1 = *(const bf16x8*)(Vr + 8);
#pragma unroll
            for (int j = 0; j < 8; ++j) {
                Vt[d0_stage + j][key_stage]     = (us)v0[j];
                Vt[d0_stage + 8 + j][key_stage] = (us)v1[j];
            }
        }
        __syncthreads();

        f32x4 s[4];
#pragma unroll
        for (int nt = 0; nt < 4; ++nt) { s[nt][0]=0.f; s[nt][1]=0.f; s[nt][2]=0.f; s[nt][3]=0.f; }
#pragma unroll
        for (int ks = 0; ks < 2; ++ks) {
#pragma unroll
            for (int nt = 0; nt < 4; ++nt) {
                bf16x8 kb = *(const bf16x8*)&Ks[nt * 16 + ll][ks * 32 + lg * 8];
                s[nt] = __builtin_amdgcn_mfma_f32_16x16x32_bf16(qa[ks], kb, s[nt], 0, 0, 0);
            }
        }

        float p[4][4];
        float corr[4];
#pragma unroll
        for (int r = 0; r < 4; ++r) {
            float mx = -INFINITY;
#pragma unroll
            for (int nt = 0; nt < 4; ++nt) {
                float svv = s[nt][r] * sc;
                int key = k0 + nt * 16 + ll;
                svv = (key < nv) ? svv : -INFINITY;
                p[nt][r] = svv;
                mx = fmaxf(mx, svv);
            }
            mx = fmaxf(mx, __shfl_xor(mx, 1));
            mx = fmaxf(mx, __shfl_xor(mx, 2));
            mx = fmaxf(mx, __shfl_xor(mx, 4));
            mx = fmaxf(mx, __shfl_xor(mx, 8));
            float mn = fmaxf(m[r], mx);
            corr[r] = __expf(m[r] - mn);
            m[r] = mn;
            float ps = 0.f;
#pragma unroll
            for (int nt = 0; nt < 4; ++nt) {
                float pv = __expf(p[nt][r] - mn);
                p[nt][r] = pv;
                ps += pv;
            }
            ps += __shfl_xor(ps, 1);
            ps += __shfl_xor(ps, 2);
            ps += __shfl_xor(ps, 4);
            ps += __shfl_xor(ps, 8);
            lsum[r] = lsum[r] * corr[r] + ps;
        }

#pragma unroll
        for (int r = 0; r < 4; ++r)
#pragma unroll
            for (int nt = 0; nt < 4; ++nt)
                Ps[wave][lg * 4 + r][nt * 16 + ll] = (us)f2b(p[nt][r]);
#pragma unroll
        for (int nt = 0; nt < 4; ++nt)
#pragma unroll
            for (int r = 0; r < 4; ++r)
                o[nt][r] *= corr[r];

#pragma unroll
        for (int ks = 0; ks < 2; ++ks) {
            bf16x8 pa = *(const bf16x8*)&Ps[wave][ll][ks * 32 + lg * 8];
#pragma unroll
            for (int nt = 0; nt < 4; ++nt) {
                bf16x8 vb = *(const bf16x8*)&Vt[nt * 16 + ll][ks * 32 + lg * 8];
                o[nt] = __builtin_amdgcn_mfma_f32_16x16x32_bf16(pa, vb, o[nt], 0, 0, 0);
            }
        }
    }

#pragma unroll
    for (int r = 0; r < 4; ++r) {
        int row = q0 + wave * 16 + lg * 4 + r;
        float inv = 1.f / lsum[r];
#pragma unroll
        for (int nt = 0; nt < 4; ++nt) {
            float val = o[nt][r] * inv;
            us uh = (us)f2b(val);
            float rem = val - b2f(uh);
            size_t base = ((size_t)b * Ss + row) * Dd + h * DHh + nt * 16 + ll;
            Oh[base] = uh;
            Ol[base] = (us)f2b(rem);
        }
    }
}

extern "C" void kernel_launch(void* const* d_in, const int* in_sizes, int n_in,
                              void* d_out, int out_size, void* d_ws, size_t ws_size,
                              hipStream_t stream) {
    const float* x     = (const float*)d_in[0];
    const int*   valid = (const int*)d_in[1];
    const float* Wq = (const float*)d_in[2];
    const float* bq = (const float*)d_in[3];
    const float* Wk = (const float*)d_in[4];
    const float* bk = (const float*)d_in[5];
    const float* Wv = (const float*)d_in[6];
    const float* bv = (const float*)d_in[7];
    const float* Wo = (const float*)d_in[8];
    const float* bo = (const float*)d_in[9];

    const size_t per = (size_t)Mm * Dd;      // 4,194,304
    const size_t wsz = (size_t)Dd * Kk;      // 1,048,576
    us* wsp  = (us*)d_ws;
    us* QKV  = wsp;                // 3*per
    us* Wt   = QKV + 3 * per;      // 3*wsz
    us* OhB  = Wt + 3 * wsz;       // per
    us* OlB  = OhB + per;          // per
    us* Woth = OlB + per;          // wsz
    us* Wotl = Woth + wsz;         // wsz

    dim3 tg(Dd / 64, Kk / 64);
    wtrans_kernel<<<tg, 256, 0, stream>>>(Wq, Wt + 0 * wsz, nullptr, 0);
    wtrans_kernel<<<tg, 256, 0, stream>>>(Wk, Wt + 1 * wsz, nullptr, 0);
    wtrans_kernel<<<tg, 256, 0, stream>>>(Wv, Wt + 2 * wsz, nullptr, 0);
    wtrans_kernel<<<tg, 256, 0, stream>>>(Wo, Woth, Wotl, 1);

    gemm_qkv_kernel<<<dim3(Dd / 128, Mm / 128, 3), 256, 0, stream>>>(x, Wt, bq, bk, bv, QKV);

    attn_mfma_kernel<<<dim3(Ss / 64, Bb * Hh), 256, 0, stream>>>(
        QKV, QKV + per, QKV + 2 * per, valid, OhB, OlB);

    gemm_final_kernel<<<dim3(Dd / 128, Mm / 128), 256, 0, stream>>>(
        OhB, OlB, Woth, Wotl, bo, (float*)d_out);
}

// Round 4
// 199.176 us; speedup vs baseline: 26.0139x; 1.0915x over previous
//
#include <hip/hip_runtime.h>
#include <hip/hip_bf16.h>
#include <math.h>

static constexpr int Bb = 2, Ss = 2048, Dd = 1024, Hh = 16, DHh = 64;
static constexpr int Mm = Bb * Ss;     // 4096
static constexpr int Kk = Dd;          // 1024

typedef __attribute__((ext_vector_type(8))) short bf16x8;
typedef __attribute__((ext_vector_type(4))) float f32x4;
typedef unsigned short us;

__device__ inline short f2b(float f) {
    __hip_bfloat16 h = __float2bfloat16(f);
    return *reinterpret_cast<short*>(&h);
}
__device__ inline float b2f(us u) {
    __hip_bfloat16 h = *reinterpret_cast<__hip_bfloat16*>(&u);
    return __bfloat162float(h);
}
__device__ inline unsigned pk2(float lo, float hi) {
    return ((unsigned)(us)f2b(hi) << 16) | (unsigned)(us)f2b(lo);
}

// ---- transpose + bf16 convert: Wt[n][k] = bf16(W[k][n]); optional hi/lo split ----
__global__ __launch_bounds__(256)
void wtrans_kernel(const float* __restrict__ W, us* __restrict__ Wth,
                   us* __restrict__ Wtl, int split)
{
    __shared__ float T[64][65];
    const int n0 = blockIdx.x * 64, k0 = blockIdx.y * 64;
    const int tid = threadIdx.x;
    const int r = tid >> 2, c0 = (tid & 3) * 16;
#pragma unroll
    for (int j = 0; j < 4; ++j) {
        float4 v = *(const float4*)(W + (size_t)(k0 + r) * Dd + n0 + c0 + 4 * j);
        T[r][c0 + 4 * j + 0] = v.x;
        T[r][c0 + 4 * j + 1] = v.y;
        T[r][c0 + 4 * j + 2] = v.z;
        T[r][c0 + 4 * j + 3] = v.w;
    }
    __syncthreads();
    us hi[16], lo[16];
#pragma unroll
    for (int j = 0; j < 16; ++j) {
        float v = T[c0 + j][r];
        us h = (us)f2b(v);
        hi[j] = h;
        if (split) lo[j] = (us)f2b(v - b2f(h));
    }
    *(bf16x8*)&Wth[(size_t)(n0 + r) * Kk + k0 + c0]     = *(bf16x8*)&hi[0];
    *(bf16x8*)&Wth[(size_t)(n0 + r) * Kk + k0 + c0 + 8] = *(bf16x8*)&hi[8];
    if (split) {
        *(bf16x8*)&Wtl[(size_t)(n0 + r) * Kk + k0 + c0]     = *(bf16x8*)&lo[0];
        *(bf16x8*)&Wtl[(size_t)(n0 + r) * Kk + k0 + c0 + 8] = *(bf16x8*)&lo[8];
    }
}

// ---- fused QKV projection: bf16 MFMA ----
// z=0 (Q), z=1 (K): scatter to (B,H,S,DH). z=2 (V): scatter TRANSPOSED to (B,H,DH,S).
__global__ __launch_bounds__(256)
void gemm_qkv_kernel(const float* __restrict__ x, const us* __restrict__ Wt,
                     const float* __restrict__ bq, const float* __restrict__ bk,
                     const float* __restrict__ bv, us* __restrict__ QKV)
{
    const int z = blockIdx.z;
    const int col0 = blockIdx.x * 128, row0 = blockIdx.y * 128;
    const int tid = threadIdx.x;
    const int wave = tid >> 6, lane = tid & 63;
    const int wr = wave >> 1, wc = wave & 1;
    const int lg = lane >> 4, ll = lane & 15;

    const float* bias = (z == 0) ? bq : (z == 1) ? bk : bv;
    const us* Wz = Wt + (size_t)z * Dd * Kk;
    us* outz = QKV + (size_t)z * Mm * Dd;

    __shared__ us As[128][40];
    __shared__ us Bs[128][40];

    f32x4 acc[4][4];
#pragma unroll
    for (int mt = 0; mt < 4; ++mt)
#pragma unroll
        for (int nt = 0; nt < 4; ++nt)
#pragma unroll
            for (int r = 0; r < 4; ++r) acc[mt][nt][r] = 0.f;

    const int ar = tid >> 2, ac = (tid & 3) * 8;

    for (int k0 = 0; k0 < Kk; k0 += 32) {
        __syncthreads();
#pragma unroll
        for (int i = 0; i < 2; ++i) {
            const int rw = ar + 64 * i;
            const float4* s4 = (const float4*)(x + (size_t)(row0 + rw) * Kk + k0 + ac);
            float4 a = s4[0], b = s4[1];
            bf16x8 t;
            t[0] = f2b(a.x); t[1] = f2b(a.y); t[2] = f2b(a.z); t[3] = f2b(a.w);
            t[4] = f2b(b.x); t[5] = f2b(b.y); t[6] = f2b(b.z); t[7] = f2b(b.w);
            *(bf16x8*)&As[rw][ac] = t;
            *(bf16x8*)&Bs[rw][ac] = *(const bf16x8*)(Wz + (size_t)(col0 + rw) * Kk + k0 + ac);
        }
        __syncthreads();

        bf16x8 af[4], bfr[4];
#pragma unroll
        for (int mt = 0; mt < 4; ++mt) af[mt]  = *(const bf16x8*)&As[wr * 64 + mt * 16 + ll][lg * 8];
#pragma unroll
        for (int nt = 0; nt < 4; ++nt) bfr[nt] = *(const bf16x8*)&Bs[wc * 64 + nt * 16 + ll][lg * 8];
#pragma unroll
        for (int mt = 0; mt < 4; ++mt)
#pragma unroll
            for (int nt = 0; nt < 4; ++nt)
                acc[mt][nt] = __builtin_amdgcn_mfma_f32_16x16x32_bf16(af[mt], bfr[nt], acc[mt][nt], 0, 0, 0);
    }

    if (z == 2) {
        // transposed scatter: V^T[(b*H+h)*DH + d][s], 4 consecutive s per lane
#pragma unroll
        for (int mt = 0; mt < 4; ++mt)
#pragma unroll
            for (int nt = 0; nt < 4; ++nt) {
                int row = row0 + wr * 64 + mt * 16 + lg * 4;   // s base (r=0..3)
                int col = col0 + wc * 64 + nt * 16 + ll;        // h*64 + d
                int b_ = row >> 11, s_ = row & 2047;
                float bv_ = bias[col];
                union { us u[4]; uint2 d2; } pk;
#pragma unroll
                for (int r = 0; r < 4; ++r) pk.u[r] = (us)f2b(acc[mt][nt][r] + bv_);
                *(uint2*)&outz[((size_t)(b_ * Hh * DHh) + col) * Ss + s_] = pk.d2;
            }
    } else {
#pragma unroll
        for (int mt = 0; mt < 4; ++mt)
#pragma unroll
            for (int nt = 0; nt < 4; ++nt)
#pragma unroll
                for (int r = 0; r < 4; ++r) {
                    int row = row0 + wr * 64 + mt * 16 + lg * 4 + r;
                    int col = col0 + wc * 64 + nt * 16 + ll;
                    float v = acc[mt][nt][r] + bias[col];
                    int b_ = row >> 11, s_ = row & 2047, h_ = col >> 6, d_ = col & 63;
                    outz[(((size_t)(b_ * Hh + h_)) * Ss + s_) * DHh + d_] = (us)f2b(v);
                }
    }
}

// ---- final GEMM, split-bf16: out = (Oh+Ol) @ (Wh+Wl) + bo, fp32 out ----
__global__ __launch_bounds__(256)
void gemm_final_kernel(const us* __restrict__ Oh, const us* __restrict__ Ol,
                       const us* __restrict__ Wth, const us* __restrict__ Wtl,
                       const float* __restrict__ bo, float* __restrict__ out)
{
    const int col0 = blockIdx.x * 128, row0 = blockIdx.y * 128;
    const int tid = threadIdx.x;
    const int wave = tid >> 6, lane = tid & 63;
    const int wr = wave >> 1, wc = wave & 1;
    const int lg = lane >> 4, ll = lane & 15;

    __shared__ us Ahs[128][40];
    __shared__ us Als[128][40];
    __shared__ us Bhs[128][40];
    __shared__ us Bls[128][40];

    f32x4 acc[4][4];
#pragma unroll
    for (int mt = 0; mt < 4; ++mt)
#pragma unroll
        for (int nt = 0; nt < 4; ++nt)
#pragma unroll
            for (int r = 0; r < 4; ++r) acc[mt][nt][r] = 0.f;

    const int ar = tid >> 2, ac = (tid & 3) * 8;

    for (int k0 = 0; k0 < Kk; k0 += 32) {
        __syncthreads();
#pragma unroll
        for (int i = 0; i < 2; ++i) {
            const int rw = ar + 64 * i;
            *(bf16x8*)&Ahs[rw][ac] = *(const bf16x8*)(Oh  + (size_t)(row0 + rw) * Kk + k0 + ac);
            *(bf16x8*)&Als[rw][ac] = *(const bf16x8*)(Ol  + (size_t)(row0 + rw) * Kk + k0 + ac);
            *(bf16x8*)&Bhs[rw][ac] = *(const bf16x8*)(Wth + (size_t)(col0 + rw) * Kk + k0 + ac);
            *(bf16x8*)&Bls[rw][ac] = *(const bf16x8*)(Wtl + (size_t)(col0 + rw) * Kk + k0 + ac);
        }
        __syncthreads();

        bf16x8 ah[4], al[4], bh[4], bl[4];
#pragma unroll
        for (int mt = 0; mt < 4; ++mt) {
            ah[mt] = *(const bf16x8*)&Ahs[wr * 64 + mt * 16 + ll][lg * 8];
            al[mt] = *(const bf16x8*)&Als[wr * 64 + mt * 16 + ll][lg * 8];
        }
#pragma unroll
        for (int nt = 0; nt < 4; ++nt) {
            bh[nt] = *(const bf16x8*)&Bhs[wc * 64 + nt * 16 + ll][lg * 8];
            bl[nt] = *(const bf16x8*)&Bls[wc * 64 + nt * 16 + ll][lg * 8];
        }
#pragma unroll
        for (int mt = 0; mt < 4; ++mt)
#pragma unroll
            for (int nt = 0; nt < 4; ++nt) {
                acc[mt][nt] = __builtin_amdgcn_mfma_f32_16x16x32_bf16(ah[mt], bh[nt], acc[mt][nt], 0, 0, 0);
                acc[mt][nt] = __builtin_amdgcn_mfma_f32_16x16x32_bf16(al[mt], bh[nt], acc[mt][nt], 0, 0, 0);
                acc[mt][nt] = __builtin_amdgcn_mfma_f32_16x16x32_bf16(ah[mt], bl[nt], acc[mt][nt], 0, 0, 0);
            }
    }

#pragma unroll
    for (int mt = 0; mt < 4; ++mt)
#pragma unroll
        for (int nt = 0; nt < 4; ++nt)
#pragma unroll
            for (int r = 0; r < 4; ++r) {
                int row = row0 + wr * 64 + mt * 16 + lg * 4 + r;
                int col = col0 + wc * 64 + nt * 16 + ll;
                out[(size_t)row * Dd + col] = acc[mt][nt][r] + bo[col];
            }
}

// ---- Flash attention: swapped QK^T, register P via shfl, V^T staged from global ----
// Q,K: (B,H,S,DH) bf16.  Vt_g: (B,H,DH,S) bf16.  Oh/Ol: (B,S,D) bf16 hi/lo.
__global__ __launch_bounds__(256)
void attn_mfma_kernel(const us* __restrict__ Q, const us* __restrict__ K,
                      const us* __restrict__ Vt_g, const int* __restrict__ valid_nums,
                      us* __restrict__ Oh, us* __restrict__ Ol)
{
    const int bh = blockIdx.y;
    const int b  = bh >> 4, h = bh & 15;
    const int q0 = blockIdx.x * 64;
    const int tid  = threadIdx.x;
    const int wave = tid >> 6;
    const int lane = tid & 63;
    const int lg = lane >> 4;
    const int ll = lane & 15;

    const int nv = valid_nums[b];
    const int ntiles = (nv + 63) >> 6;

    const us* Qb = Q    + (size_t)bh * Ss * DHh;
    const us* Kb = K    + (size_t)bh * Ss * DHh;
    const us* Vb = Vt_g + (size_t)bh * DHh * Ss;   // [d][s]

    __shared__ us Ks[64][68];   // [key][dim], 34-dword row stride
    __shared__ us Vs[64][68];   // [dim][key]

    // Q B-fragments (B[k=dh][n=q]): lane (lg,ll) holds Q[q0+w*16+ll][ks*32+lg*8+j]
    bf16x8 qa[2];
    {
        const us* qrow = Qb + (size_t)(q0 + wave * 16 + ll) * DHh;
        qa[0] = *(const bf16x8*)(qrow + lg * 8);
        qa[1] = *(const bf16x8*)(qrow + 32 + lg * 8);
    }

    f32x4 o[4];
#pragma unroll
    for (int nt = 0; nt < 4; ++nt) { o[nt][0]=0.f; o[nt][1]=0.f; o[nt][2]=0.f; o[nt][3]=0.f; }
    float mq = -INFINITY, lq = 0.f;        // softmax state for q = ll (replicated x4)

    const int srow = tid >> 2;             // 0..63
    const int scol = (tid & 3) * 16;
    const float sc = 0.125f;               // 1/sqrt(64)

    for (int kt = 0; kt < ntiles; ++kt) {
        const int k0 = kt * 64;
        __syncthreads();
        {
            const us* Kr = Kb + (size_t)(k0 + srow) * DHh + scol;
            *(bf16x8*)&Ks[srow][scol]     = *(const bf16x8*)Kr;
            *(bf16x8*)&Ks[srow][scol + 8] = *(const bf16x8*)(Kr + 8);
            const us* Vr = Vb + (size_t)srow * Ss + k0 + scol;
            *(bf16x8*)&Vs[srow][scol]     = *(const bf16x8*)Vr;
            *(bf16x8*)&Vs[srow][scol + 8] = *(const bf16x8*)(Vr + 8);
        }
        __syncthreads();

        // S^T = K Q^T : s[nt][r] = S[key = k0+nt*16+lg*4+r][q = ll]
        f32x4 s[4];
#pragma unroll
        for (int nt = 0; nt < 4; ++nt) { s[nt][0]=0.f; s[nt][1]=0.f; s[nt][2]=0.f; s[nt][3]=0.f; }
#pragma unroll
        for (int ks = 0; ks < 2; ++ks) {
#pragma unroll
            for (int nt = 0; nt < 4; ++nt) {
                bf16x8 kf = *(const bf16x8*)&Ks[nt * 16 + ll][ks * 32 + lg * 8];
                s[nt] = __builtin_amdgcn_mfma_f32_16x16x32_bf16(kf, qa[ks], s[nt], 0, 0, 0);
            }
        }

        // mask + scale, column softmax for q=ll
        float p[4][4];
        float mx = -INFINITY;
#pragma unroll
        for (int nt = 0; nt < 4; ++nt)
#pragma unroll
            for (int r = 0; r < 4; ++r) {
                int key = k0 + nt * 16 + lg * 4 + r;
                float v = (key < nv) ? s[nt][r] * sc : -INFINITY;
                p[nt][r] = v;
                mx = fmaxf(mx, v);
            }
        mx = fmaxf(mx, __shfl_xor(mx, 16));
        mx = fmaxf(mx, __shfl_xor(mx, 32));
        float mn = fmaxf(mq, mx);
        float corr = __expf(mq - mn);       // mq=-inf -> 0
        mq = mn;
        float ps = 0.f;
#pragma unroll
        for (int nt = 0; nt < 4; ++nt)
#pragma unroll
            for (int r = 0; r < 4; ++r) {
                float pv = __expf(p[nt][r] - mn);
                p[nt][r] = pv;
                ps += pv;
            }
        ps += __shfl_xor(ps, 16);
        ps += __shfl_xor(ps, 32);
        lq = lq * corr + ps;

        // pack P rows (key-contiguous per lane) into bf16-pair dwords
        unsigned dw[4][2];
#pragma unroll
        for (int nt = 0; nt < 4; ++nt) {
            dw[nt][0] = pk2(p[nt][0], p[nt][1]);
            dw[nt][1] = pk2(p[nt][2], p[nt][3]);
        }

        // rescale O (rows q = lg*4+r): fetch corr for that q from a lane with ll = q
        float corr4[4];
#pragma unroll
        for (int r = 0; r < 4; ++r) corr4[r] = __shfl(corr, lg * 16 + lg * 4 + r);
#pragma unroll
        for (int nt = 0; nt < 4; ++nt)
#pragma unroll
            for (int r = 0; r < 4; ++r) o[nt][r] *= corr4[r];

        // build P A-fragments via lane gather, then O += P V
        const int sA = ((2 * lg) & 3) * 16 + ll;
        const int sB = ((2 * lg + 1) & 3) * 16 + ll;
        const bool hi = (lg & 2);
#pragma unroll
        for (int ks = 0; ks < 2; ++ks) {
            unsigned a0 = (unsigned)__shfl((int)dw[2 * ks][0],     sA);
            unsigned a1 = (unsigned)__shfl((int)dw[2 * ks][1],     sA);
            unsigned a2 = (unsigned)__shfl((int)dw[2 * ks][0],     sB);
            unsigned a3 = (unsigned)__shfl((int)dw[2 * ks][1],     sB);
            unsigned b0 = (unsigned)__shfl((int)dw[2 * ks + 1][0], sA);
            unsigned b1 = (unsigned)__shfl((int)dw[2 * ks + 1][1], sA);
            unsigned b2 = (unsigned)__shfl((int)dw[2 * ks + 1][0], sB);
            unsigned b3 = (unsigned)__shfl((int)dw[2 * ks + 1][1], sB);
            union { unsigned w[4]; bf16x8 v; } pa;
            pa.w[0] = hi ? b0 : a0;
            pa.w[1] = hi ? b1 : a1;
            pa.w[2] = hi ? b2 : a2;
            pa.w[3] = hi ? b3 : a3;
#pragma unroll
            for (int nt = 0; nt < 4; ++nt) {
                bf16x8 vb = *(const bf16x8*)&Vs[nt * 16 + ll][ks * 32 + lg * 8];
                o[nt] = __builtin_amdgcn_mfma_f32_16x16x32_bf16(pa.v, vb, o[nt], 0, 0, 0);
            }
        }
    }

    // epilogue: O[q=lg*4+r][d=nt*16+ll], fetch lsum for q from lane with ll=q
    float linv[4];
#pragma unroll
    for (int r = 0; r < 4; ++r) linv[r] = 1.f / __shfl(lq, lg * 16 + lg * 4 + r);
#pragma unroll
    for (int r = 0; r < 4; ++r) {
        int row = q0 + wave * 16 + lg * 4 + r;
#pragma unroll
        for (int nt = 0; nt < 4; ++nt) {
            float val = o[nt][r] * linv[r];
            us uh = (us)f2b(val);
            float rem = val - b2f(uh);
            size_t base = ((size_t)b * Ss + row) * Dd + h * DHh + nt * 16 + ll;
            Oh[base] = uh;
            Ol[base] = (us)f2b(rem);
        }
    }
}

extern "C" void kernel_launch(void* const* d_in, const int* in_sizes, int n_in,
                              void* d_out, int out_size, void* d_ws, size_t ws_size,
                              hipStream_t stream) {
    const float* x     = (const float*)d_in[0];
    const int*   valid = (const int*)d_in[1];
    const float* Wq = (const float*)d_in[2];
    const float* bq = (const float*)d_in[3];
    const float* Wk = (const float*)d_in[4];
    const float* bk = (const float*)d_in[5];
    const float* Wv = (const float*)d_in[6];
    const float* bv = (const float*)d_in[7];
    const float* Wo = (const float*)d_in[8];
    const float* bo = (const float*)d_in[9];

    const size_t per = (size_t)Mm * Dd;      // 4,194,304
    const size_t wsz = (size_t)Dd * Kk;      // 1,048,576
    us* wsp  = (us*)d_ws;
    us* QKV  = wsp;                // 3*per  (Q,K natural; V transposed)
    us* Wt   = QKV + 3 * per;      // 3*wsz
    us* OhB  = Wt + 3 * wsz;       // per
    us* OlB  = OhB + per;          // per
    us* Woth = OlB + per;          // wsz
    us* Wotl = Woth + wsz;         // wsz

    dim3 tg(Dd / 64, Kk / 64);
    wtrans_kernel<<<tg, 256, 0, stream>>>(Wq, Wt + 0 * wsz, nullptr, 0);
    wtrans_kernel<<<tg, 256, 0, stream>>>(Wk, Wt + 1 * wsz, nullptr, 0);
    wtrans_kernel<<<tg, 256, 0, stream>>>(Wv, Wt + 2 * wsz, nullptr, 0);
    wtrans_kernel<<<tg, 256, 0, stream>>>(Wo, Woth, Wotl, 1);

    gemm_qkv_kernel<<<dim3(Dd / 128, Mm / 128, 3), 256, 0, stream>>>(x, Wt, bq, bk, bv, QKV);

    attn_mfma_kernel<<<dim3(Ss / 64, Bb * Hh), 256, 0, stream>>>(
        QKV, QKV + per, QKV + 2 * per, valid, OhB, OlB);

    gemm_final_kernel<<<dim3(Dd / 128, Mm / 128), 256, 0, stream>>>(
        OhB, OlB, Woth, Wotl, bo, (float*)d_out);
}

// Round 5
// 166.090 us; speedup vs baseline: 31.1960x; 1.1992x over previous
//
#include <hip/hip_runtime.h>
#include <hip/hip_bf16.h>
#include <math.h>

static constexpr int Bb = 2, Ss = 2048, Dd = 1024, Hh = 16, DHh = 64;
static constexpr int Mm = Bb * Ss;     // 4096
static constexpr int Kk = Dd;          // 1024

typedef __attribute__((ext_vector_type(8))) short bf16x8;
typedef __attribute__((ext_vector_type(4))) float f32x4;
typedef unsigned short us;

__device__ inline short f2b(float f) {
    __hip_bfloat16 h = __float2bfloat16(f);
    return *reinterpret_cast<short*>(&h);
}
__device__ inline float b2f(us u) {
    __hip_bfloat16 h = *reinterpret_cast<__hip_bfloat16*>(&u);
    return __bfloat162float(h);
}
__device__ inline unsigned pk2(float lo, float hi) {
    return ((unsigned)(us)f2b(hi) << 16) | (unsigned)(us)f2b(lo);
}

// async global->LDS, 16B per lane; dst is wave-uniform base (HW adds lane*16)
__device__ inline void gload16(us* lds, const us* g) {
    __builtin_amdgcn_global_load_lds(
        (const __attribute__((address_space(1))) void*)g,
        (__attribute__((address_space(3))) void*)lds,
        16, 0, 0);
}

// ---- x fp32 -> bf16 (one-shot; identical rounding to the old per-tile convert) ----
__global__ __launch_bounds__(256)
void xconv_kernel(const float* __restrict__ x, us* __restrict__ xb)
{
    const size_t i = ((size_t)blockIdx.x * 256 + threadIdx.x) * 8;
    float4 a = *(const float4*)(x + i);
    float4 b = *(const float4*)(x + i + 4);
    bf16x8 t;
    t[0] = f2b(a.x); t[1] = f2b(a.y); t[2] = f2b(a.z); t[3] = f2b(a.w);
    t[4] = f2b(b.x); t[5] = f2b(b.y); t[6] = f2b(b.z); t[7] = f2b(b.w);
    *(bf16x8*)(xb + i) = t;
}

// ---- transpose + bf16 convert: Wt[n][k] = bf16(W[k][n]); optional hi/lo split ----
__global__ __launch_bounds__(256)
void wtrans_kernel(const float* __restrict__ W, us* __restrict__ Wth,
                   us* __restrict__ Wtl, int split)
{
    __shared__ float T[64][65];
    const int n0 = blockIdx.x * 64, k0 = blockIdx.y * 64;
    const int tid = threadIdx.x;
    const int r = tid >> 2, c0 = (tid & 3) * 16;
#pragma unroll
    for (int j = 0; j < 4; ++j) {
        float4 v = *(const float4*)(W + (size_t)(k0 + r) * Dd + n0 + c0 + 4 * j);
        T[r][c0 + 4 * j + 0] = v.x;
        T[r][c0 + 4 * j + 1] = v.y;
        T[r][c0 + 4 * j + 2] = v.z;
        T[r][c0 + 4 * j + 3] = v.w;
    }
    __syncthreads();
    us hi[16], lo[16];
#pragma unroll
    for (int j = 0; j < 16; ++j) {
        float v = T[c0 + j][r];
        us h = (us)f2b(v);
        hi[j] = h;
        if (split) lo[j] = (us)f2b(v - b2f(h));
    }
    *(bf16x8*)&Wth[(size_t)(n0 + r) * Kk + k0 + c0]     = *(bf16x8*)&hi[0];
    *(bf16x8*)&Wth[(size_t)(n0 + r) * Kk + k0 + c0 + 8] = *(bf16x8*)&hi[8];
    if (split) {
        *(bf16x8*)&Wtl[(size_t)(n0 + r) * Kk + k0 + c0]     = *(bf16x8*)&lo[0];
        *(bf16x8*)&Wtl[(size_t)(n0 + r) * Kk + k0 + c0 + 8] = *(bf16x8*)&lo[8];
    }
}

// ---- fused QKV GEMM, m97 structure: 128x128 tile, BK=64, global_load_lds ----
// A = xb (4096x1024 bf16), B = Wt (3072x1024 bf16, n-major). N-block selects z.
// z=0 Q, z=1 K: scatter (B,H,S,DH). z=2 V: transposed scatter (B,H,DH,S).
__global__ __launch_bounds__(256)
void gemm_qkv_kernel(const us* __restrict__ xb, const us* __restrict__ Wt,
                     const float* __restrict__ bq, const float* __restrict__ bk,
                     const float* __restrict__ bv, us* __restrict__ QKV)
{
    __shared__ us As[128 * 64];
    __shared__ us Bs[128 * 64];
    const int tid = threadIdx.x;
    const int wave = tid >> 6, lane = tid & 63;
    const int wr = wave >> 1, wc = wave & 1;
    const int lg = lane >> 4, ll = lane & 15;
    const int col0 = blockIdx.x * 128;           // 0..3071
    const int row0 = blockIdx.y * 128;

    f32x4 acc[4][4];
#pragma unroll
    for (int mt = 0; mt < 4; ++mt)
#pragma unroll
        for (int nt = 0; nt < 4; ++nt)
#pragma unroll
            for (int r = 0; r < 4; ++r) acc[mt][nt][r] = 0.f;

    // staging: instr i of wave covers LDS rows wave*32+i*8 .. +8 (linear [row][64])
    const us* Ag = xb + (size_t)(row0 + wave * 32 + (lane >> 3)) * Kk + (lane & 7) * 8;
    const us* Bg = Wt + (size_t)(col0 + wave * 32 + (lane >> 3)) * Kk + (lane & 7) * 8;
    us* Ad = &As[(wave * 4) * 512];
    us* Bd = &Bs[(wave * 4) * 512];

    for (int k0 = 0; k0 < Kk; k0 += 64) {
        __syncthreads();
#pragma unroll
        for (int i = 0; i < 4; ++i) {
            gload16(Ad + i * 512, Ag + (size_t)(i * 8) * Kk + k0);
            gload16(Bd + i * 512, Bg + (size_t)(i * 8) * Kk + k0);
        }
        __syncthreads();
#pragma unroll
        for (int ks = 0; ks < 2; ++ks) {
            bf16x8 af[4], bfr[4];
#pragma unroll
            for (int mt = 0; mt < 4; ++mt)
                af[mt] = *(const bf16x8*)&As[(wr * 64 + mt * 16 + ll) * 64 + ks * 32 + lg * 8];
#pragma unroll
            for (int nt = 0; nt < 4; ++nt)
                bfr[nt] = *(const bf16x8*)&Bs[(wc * 64 + nt * 16 + ll) * 64 + ks * 32 + lg * 8];
#pragma unroll
            for (int mt = 0; mt < 4; ++mt)
#pragma unroll
                for (int nt = 0; nt < 4; ++nt)
                    acc[mt][nt] = __builtin_amdgcn_mfma_f32_16x16x32_bf16(af[mt], bfr[nt], acc[mt][nt], 0, 0, 0);
        }
    }

    const int z = col0 >> 10;                 // uniform per block (1024 % 128 == 0)
    const int c0 = col0 & 1023;
    const float* bias = (z == 0) ? bq : (z == 1) ? bk : bv;
    us* outz = QKV + (size_t)z * Mm * Dd;

    if (z == 2) {
#pragma unroll
        for (int mt = 0; mt < 4; ++mt)
#pragma unroll
            for (int nt = 0; nt < 4; ++nt) {
                int row = row0 + wr * 64 + mt * 16 + lg * 4;      // s base (r=0..3)
                int col = c0 + wc * 64 + nt * 16 + ll;            // h*64 + d
                int b_ = row >> 11, s_ = row & 2047;
                float bv_ = bias[col];
                union { us u[4]; uint2 d2; } pk;
#pragma unroll
                for (int r = 0; r < 4; ++r) pk.u[r] = (us)f2b(acc[mt][nt][r] + bv_);
                *(uint2*)&outz[((size_t)(b_ * Hh * DHh) + col) * Ss + s_] = pk.d2;
            }
    } else {
#pragma unroll
        for (int mt = 0; mt < 4; ++mt)
#pragma unroll
            for (int nt = 0; nt < 4; ++nt)
#pragma unroll
                for (int r = 0; r < 4; ++r) {
                    int row = row0 + wr * 64 + mt * 16 + lg * 4 + r;
                    int col = c0 + wc * 64 + nt * 16 + ll;
                    float v = acc[mt][nt][r] + bias[col];
                    int b_ = row >> 11, s_ = row & 2047, h_ = col >> 6, d_ = col & 63;
                    outz[(((size_t)(b_ * Hh + h_)) * Ss + s_) * DHh + d_] = (us)f2b(v);
                }
    }
}

// ---- final GEMM, split-bf16, m97 structure: 128x64 tile, BK=64, global_load_lds ----
__global__ __launch_bounds__(256)
void gemm_final_kernel(const us* __restrict__ Oh, const us* __restrict__ Ol,
                       const us* __restrict__ Wth, const us* __restrict__ Wtl,
                       const float* __restrict__ bo, float* __restrict__ out)
{
    __shared__ us AhS[128 * 64];
    __shared__ us AlS[128 * 64];
    __shared__ us BhS[64 * 64];
    __shared__ us BlS[64 * 64];
    const int tid = threadIdx.x;
    const int wave = tid >> 6, lane = tid & 63;
    const int wr = wave >> 1, wc = wave & 1;
    const int lg = lane >> 4, ll = lane & 15;
    const int col0 = blockIdx.x * 64;            // over N=1024
    const int row0 = blockIdx.y * 128;

    f32x4 acc[4][2];
#pragma unroll
    for (int mt = 0; mt < 4; ++mt)
#pragma unroll
        for (int nt = 0; nt < 2; ++nt)
#pragma unroll
            for (int r = 0; r < 4; ++r) acc[mt][nt][r] = 0.f;

    const size_t aoff = (size_t)(row0 + wave * 32 + (lane >> 3)) * Kk + (lane & 7) * 8;
    const size_t boff = (size_t)(col0 + wave * 16 + (lane >> 3)) * Kk + (lane & 7) * 8;
    const us* Ahg = Oh + aoff;
    const us* Alg = Ol + aoff;
    const us* Bhg = Wth + boff;
    const us* Blg = Wtl + boff;
    us* AhD = &AhS[(wave * 4) * 512];
    us* AlD = &AlS[(wave * 4) * 512];
    us* BhD = &BhS[(wave * 2) * 512];
    us* BlD = &BlS[(wave * 2) * 512];

    for (int k0 = 0; k0 < Kk; k0 += 64) {
        __syncthreads();
#pragma unroll
        for (int i = 0; i < 4; ++i) {
            gload16(AhD + i * 512, Ahg + (size_t)(i * 8) * Kk + k0);
            gload16(AlD + i * 512, Alg + (size_t)(i * 8) * Kk + k0);
        }
#pragma unroll
        for (int j = 0; j < 2; ++j) {
            gload16(BhD + j * 512, Bhg + (size_t)(j * 8) * Kk + k0);
            gload16(BlD + j * 512, Blg + (size_t)(j * 8) * Kk + k0);
        }
        __syncthreads();
#pragma unroll
        for (int ks = 0; ks < 2; ++ks) {
            bf16x8 ah[4], al[4], bh[2], bl[2];
#pragma unroll
            for (int mt = 0; mt < 4; ++mt) {
                ah[mt] = *(const bf16x8*)&AhS[(wr * 64 + mt * 16 + ll) * 64 + ks * 32 + lg * 8];
                al[mt] = *(const bf16x8*)&AlS[(wr * 64 + mt * 16 + ll) * 64 + ks * 32 + lg * 8];
            }
#pragma unroll
            for (int nt = 0; nt < 2; ++nt) {
                bh[nt] = *(const bf16x8*)&BhS[(wc * 32 + nt * 16 + ll) * 64 + ks * 32 + lg * 8];
                bl[nt] = *(const bf16x8*)&BlS[(wc * 32 + nt * 16 + ll) * 64 + ks * 32 + lg * 8];
            }
#pragma unroll
            for (int mt = 0; mt < 4; ++mt)
#pragma unroll
                for (int nt = 0; nt < 2; ++nt) {
                    acc[mt][nt] = __builtin_amdgcn_mfma_f32_16x16x32_bf16(ah[mt], bh[nt], acc[mt][nt], 0, 0, 0);
                    acc[mt][nt] = __builtin_amdgcn_mfma_f32_16x16x32_bf16(al[mt], bh[nt], acc[mt][nt], 0, 0, 0);
                    acc[mt][nt] = __builtin_amdgcn_mfma_f32_16x16x32_bf16(ah[mt], bl[nt], acc[mt][nt], 0, 0, 0);
                }
        }
    }

#pragma unroll
    for (int mt = 0; mt < 4; ++mt)
#pragma unroll
        for (int nt = 0; nt < 2; ++nt)
#pragma unroll
            for (int r = 0; r < 4; ++r) {
                int row = row0 + wr * 64 + mt * 16 + lg * 4 + r;
                int col = col0 + wc * 32 + nt * 16 + ll;
                out[(size_t)row * Dd + col] = acc[mt][nt][r] + bo[col];
            }
}

// ---- Flash attention: swapped QK^T, register P via shfl, V^T staged from global ----
__global__ __launch_bounds__(256)
void attn_mfma_kernel(const us* __restrict__ Q, const us* __restrict__ K,
                      const us* __restrict__ Vt_g, const int* __restrict__ valid_nums,
                      us* __restrict__ Oh, us* __restrict__ Ol)
{
    const int bh = blockIdx.y;
    const int b  = bh >> 4, h = bh & 15;
    const int q0 = blockIdx.x * 64;
    const int tid  = threadIdx.x;
    const int wave = tid >> 6;
    const int lane = tid & 63;
    const int lg = lane >> 4;
    const int ll = lane & 15;

    const int nv = valid_nums[b];
    const int ntiles = (nv + 63) >> 6;

    const us* Qb = Q    + (size_t)bh * Ss * DHh;
    const us* Kb = K    + (size_t)bh * Ss * DHh;
    const us* Vb = Vt_g + (size_t)bh * DHh * Ss;   // [d][s]

    __shared__ us Ks[64][68];
    __shared__ us Vs[64][68];

    bf16x8 qa[2];
    {
        const us* qrow = Qb + (size_t)(q0 + wave * 16 + ll) * DHh;
        qa[0] = *(const bf16x8*)(qrow + lg * 8);
        qa[1] = *(const bf16x8*)(qrow + 32 + lg * 8);
    }

    f32x4 o[4];
#pragma unroll
    for (int nt = 0; nt < 4; ++nt) { o[nt][0]=0.f; o[nt][1]=0.f; o[nt][2]=0.f; o[nt][3]=0.f; }
    float mq = -INFINITY, lq = 0.f;

    const int srow = tid >> 2;
    const int scol = (tid & 3) * 16;
    const float sc = 0.125f;

    for (int kt = 0; kt < ntiles; ++kt) {
        const int k0 = kt * 64;
        __syncthreads();
        {
            const us* Kr = Kb + (size_t)(k0 + srow) * DHh + scol;
            *(bf16x8*)&Ks[srow][scol]     = *(const bf16x8*)Kr;
            *(bf16x8*)&Ks[srow][scol + 8] = *(const bf16x8*)(Kr + 8);
            const us* Vr = Vb + (size_t)srow * Ss + k0 + scol;
            *(bf16x8*)&Vs[srow][scol]     = *(const bf16x8*)Vr;
            *(bf16x8*)&Vs[srow][scol + 8] = *(const bf16x8*)(Vr + 8);
        }
        __syncthreads();

        f32x4 s[4];
#pragma unroll
        for (int nt = 0; nt < 4; ++nt) { s[nt][0]=0.f; s[nt][1]=0.f; s[nt][2]=0.f; s[nt][3]=0.f; }
#pragma unroll
        for (int ks = 0; ks < 2; ++ks) {
#pragma unroll
            for (int nt = 0; nt < 4; ++nt) {
                bf16x8 kf = *(const bf16x8*)&Ks[nt * 16 + ll][ks * 32 + lg * 8];
                s[nt] = __builtin_amdgcn_mfma_f32_16x16x32_bf16(kf, qa[ks], s[nt], 0, 0, 0);
            }
        }

        float p[4][4];
        float mx = -INFINITY;
#pragma unroll
        for (int nt = 0; nt < 4; ++nt)
#pragma unroll
            for (int r = 0; r < 4; ++r) {
                int key = k0 + nt * 16 + lg * 4 + r;
                float v = (key < nv) ? s[nt][r] * sc : -INFINITY;
                p[nt][r] = v;
                mx = fmaxf(mx, v);
            }
        mx = fmaxf(mx, __shfl_xor(mx, 16));
        mx = fmaxf(mx, __shfl_xor(mx, 32));
        float mn = fmaxf(mq, mx);
        float corr = __expf(mq - mn);
        mq = mn;
        float ps = 0.f;
#pragma unroll
        for (int nt = 0; nt < 4; ++nt)
#pragma unroll
            for (int r = 0; r < 4; ++r) {
                float pv = __expf(p[nt][r] - mn);
                p[nt][r] = pv;
                ps += pv;
            }
        ps += __shfl_xor(ps, 16);
        ps += __shfl_xor(ps, 32);
        lq = lq * corr + ps;

        unsigned dw[4][2];
#pragma unroll
        for (int nt = 0; nt < 4; ++nt) {
            dw[nt][0] = pk2(p[nt][0], p[nt][1]);
            dw[nt][1] = pk2(p[nt][2], p[nt][3]);
        }

        float corr4[4];
#pragma unroll
        for (int r = 0; r < 4; ++r) corr4[r] = __shfl(corr, lg * 16 + lg * 4 + r);
#pragma unroll
        for (int nt = 0; nt < 4; ++nt)
#pragma unroll
            for (int r = 0; r < 4; ++r) o[nt][r] *= corr4[r];

        const int sA = ((2 * lg) & 3) * 16 + ll;
        const int sB = ((2 * lg + 1) & 3) * 16 + ll;
        const bool hi = (lg & 2);
#pragma unroll
        for (int ks = 0; ks < 2; ++ks) {
            unsigned a0 = (unsigned)__shfl((int)dw[2 * ks][0],     sA);
            unsigned a1 = (unsigned)__shfl((int)dw[2 * ks][1],     sA);
            unsigned a2 = (unsigned)__shfl((int)dw[2 * ks][0],     sB);
            unsigned a3 = (unsigned)__shfl((int)dw[2 * ks][1],     sB);
            unsigned b0 = (unsigned)__shfl((int)dw[2 * ks + 1][0], sA);
            unsigned b1 = (unsigned)__shfl((int)dw[2 * ks + 1][1], sA);
            unsigned b2 = (unsigned)__shfl((int)dw[2 * ks + 1][0], sB);
            unsigned b3 = (unsigned)__shfl((int)dw[2 * ks + 1][1], sB);
            union { unsigned w[4]; bf16x8 v; } pa;
            pa.w[0] = hi ? b0 : a0;
            pa.w[1] = hi ? b1 : a1;
            pa.w[2] = hi ? b2 : a2;
            pa.w[3] = hi ? b3 : a3;
#pragma unroll
            for (int nt = 0; nt < 4; ++nt) {
                bf16x8 vb = *(const bf16x8*)&Vs[nt * 16 + ll][ks * 32 + lg * 8];
                o[nt] = __builtin_amdgcn_mfma_f32_16x16x32_bf16(pa.v, vb, o[nt], 0, 0, 0);
            }
        }
    }

    float linv[4];
#pragma unroll
    for (int r = 0; r < 4; ++r) linv[r] = 1.f / __shfl(lq, lg * 16 + lg * 4 + r);
#pragma unroll
    for (int r = 0; r < 4; ++r) {
        int row = q0 + wave * 16 + lg * 4 + r;
#pragma unroll
        for (int nt = 0; nt < 4; ++nt) {
            float val = o[nt][r] * linv[r];
            us uh = (us)f2b(val);
            float rem = val - b2f(uh);
            size_t base = ((size_t)b * Ss + row) * Dd + h * DHh + nt * 16 + ll;
            Oh[base] = uh;
            Ol[base] = (us)f2b(rem);
        }
    }
}

extern "C" void kernel_launch(void* const* d_in, const int* in_sizes, int n_in,
                              void* d_out, int out_size, void* d_ws, size_t ws_size,
                              hipStream_t stream) {
    const float* x     = (const float*)d_in[0];
    const int*   valid = (const int*)d_in[1];
    const float* Wq = (const float*)d_in[2];
    const float* bq = (const float*)d_in[3];
    const float* Wk = (const float*)d_in[4];
    const float* bk = (const float*)d_in[5];
    const float* Wv = (const float*)d_in[6];
    const float* bv = (const float*)d_in[7];
    const float* Wo = (const float*)d_in[8];
    const float* bo = (const float*)d_in[9];

    const size_t per = (size_t)Mm * Dd;      // 4,194,304
    const size_t wsz = (size_t)Dd * Kk;      // 1,048,576
    us* wsp  = (us*)d_ws;
    us* QKV  = wsp;                // 3*per  (Q,K natural; V transposed)
    us* Wt   = QKV + 3 * per;      // 3*wsz
    us* OhB  = Wt + 3 * wsz;       // per
    us* OlB  = OhB + per;          // per
    us* Woth = OlB + per;          // wsz
    us* Wotl = Woth + wsz;         // wsz
    us* xb   = Wotl + wsz;         // per

    xconv_kernel<<<(Mm * Kk) / (256 * 8), 256, 0, stream>>>(x, xb);

    dim3 tg(Dd / 64, Kk / 64);
    wtrans_kernel<<<tg, 256, 0, stream>>>(Wq, Wt + 0 * wsz, nullptr, 0);
    wtrans_kernel<<<tg, 256, 0, stream>>>(Wk, Wt + 1 * wsz, nullptr, 0);
    wtrans_kernel<<<tg, 256, 0, stream>>>(Wv, Wt + 2 * wsz, nullptr, 0);
    wtrans_kernel<<<tg, 256, 0, stream>>>(Wo, Woth, Wotl, 1);

    gemm_qkv_kernel<<<dim3(3 * Dd / 128, Mm / 128), 256, 0, stream>>>(
        xb, Wt, bq, bk, bv, QKV);

    attn_mfma_kernel<<<dim3(Ss / 64, Bb * Hh), 256, 0, stream>>>(
        QKV, QKV + per, QKV + 2 * per, valid, OhB, OlB);

    gemm_final_kernel<<<dim3(Dd / 64, Mm / 128), 256, 0, stream>>>(
        OhB, OlB, Woth, Wotl, bo, (float*)d_out);
}

// Round 6
// 155.138 us; speedup vs baseline: 33.3982x; 1.0706x over previous
//
#include <hip/hip_runtime.h>
#include <hip/hip_bf16.h>
#include <math.h>

static constexpr int Bb = 2, Ss = 2048, Dd = 1024, Hh = 16, DHh = 64;
static constexpr int Mm = Bb * Ss;     // 4096
static constexpr int Kk = Dd;          // 1024

typedef __attribute__((ext_vector_type(8))) short bf16x8;
typedef __attribute__((ext_vector_type(4))) float f32x4;
typedef unsigned short us;

__device__ inline short f2b(float f) {
    __hip_bfloat16 h = __float2bfloat16(f);
    return *reinterpret_cast<short*>(&h);
}
__device__ inline float b2f(us u) {
    __hip_bfloat16 h = *reinterpret_cast<__hip_bfloat16*>(&u);
    return __bfloat162float(h);
}
__device__ inline unsigned pk2(float lo, float hi) {
    return ((unsigned)(us)f2b(hi) << 16) | (unsigned)(us)f2b(lo);
}

// async global->LDS, 16B per lane; dst is wave-uniform base (HW adds lane*16)
__device__ inline void gload16(us* lds, const us* g) {
    __builtin_amdgcn_global_load_lds(
        (const __attribute__((address_space(1))) void*)g,
        (__attribute__((address_space(3))) void*)lds,
        16, 0, 0);
}

// ---- x fp32 -> bf16 ----
__global__ __launch_bounds__(256)
void xconv_kernel(const float* __restrict__ x, us* __restrict__ xb)
{
    const size_t i = ((size_t)blockIdx.x * 256 + threadIdx.x) * 8;
    float4 a = *(const float4*)(x + i);
    float4 b = *(const float4*)(x + i + 4);
    bf16x8 t;
    t[0] = f2b(a.x); t[1] = f2b(a.y); t[2] = f2b(a.z); t[3] = f2b(a.w);
    t[4] = f2b(b.x); t[5] = f2b(b.y); t[6] = f2b(b.z); t[7] = f2b(b.w);
    *(bf16x8*)(xb + i) = t;
}

// ---- fused transpose+convert for all 4 weights (z=0..3); z==3 hi/lo split ----
__global__ __launch_bounds__(256)
void wtrans_kernel(const float* __restrict__ Wq, const float* __restrict__ Wk,
                   const float* __restrict__ Wv, const float* __restrict__ Wo,
                   us* __restrict__ Wt, us* __restrict__ Woth, us* __restrict__ Wotl)
{
    __shared__ float T[64][65];
    const int z = blockIdx.z;
    const float* W = (z == 0) ? Wq : (z == 1) ? Wk : (z == 2) ? Wv : Wo;
    const int split = (z == 3);
    us* dh = split ? Woth : (Wt + (size_t)z * Dd * Kk);
    us* dl = Wotl;

    const int n0 = blockIdx.x * 64, k0 = blockIdx.y * 64;
    const int tid = threadIdx.x;
    const int r = tid >> 2, c0 = (tid & 3) * 16;
#pragma unroll
    for (int j = 0; j < 4; ++j) {
        float4 v = *(const float4*)(W + (size_t)(k0 + r) * Dd + n0 + c0 + 4 * j);
        T[r][c0 + 4 * j + 0] = v.x;
        T[r][c0 + 4 * j + 1] = v.y;
        T[r][c0 + 4 * j + 2] = v.z;
        T[r][c0 + 4 * j + 3] = v.w;
    }
    __syncthreads();
    us hi[16], lo[16];
#pragma unroll
    for (int j = 0; j < 16; ++j) {
        float v = T[c0 + j][r];
        us h = (us)f2b(v);
        hi[j] = h;
        if (split) lo[j] = (us)f2b(v - b2f(h));
    }
    *(bf16x8*)&dh[(size_t)(n0 + r) * Kk + k0 + c0]     = *(bf16x8*)&hi[0];
    *(bf16x8*)&dh[(size_t)(n0 + r) * Kk + k0 + c0 + 8] = *(bf16x8*)&hi[8];
    if (split) {
        *(bf16x8*)&dl[(size_t)(n0 + r) * Kk + k0 + c0]     = *(bf16x8*)&lo[0];
        *(bf16x8*)&dl[(size_t)(n0 + r) * Kk + k0 + c0 + 8] = *(bf16x8*)&lo[8];
    }
}

// ---- fused QKV GEMM, m97 structure. Q is PRE-SCALED by 1/sqrt(DH). ----
__global__ __launch_bounds__(256)
void gemm_qkv_kernel(const us* __restrict__ xb, const us* __restrict__ Wt,
                     const float* __restrict__ bq, const float* __restrict__ bk,
                     const float* __restrict__ bv, us* __restrict__ QKV)
{
    __shared__ us As[128 * 64];
    __shared__ us Bs[128 * 64];
    const int tid = threadIdx.x;
    const int wave = tid >> 6, lane = tid & 63;
    const int wr = wave >> 1, wc = wave & 1;
    const int lg = lane >> 4, ll = lane & 15;
    const int col0 = blockIdx.x * 128;           // 0..3071
    const int row0 = blockIdx.y * 128;

    f32x4 acc[4][4];
#pragma unroll
    for (int mt = 0; mt < 4; ++mt)
#pragma unroll
        for (int nt = 0; nt < 4; ++nt)
#pragma unroll
            for (int r = 0; r < 4; ++r) acc[mt][nt][r] = 0.f;

    const us* Ag = xb + (size_t)(row0 + wave * 32 + (lane >> 3)) * Kk + (lane & 7) * 8;
    const us* Bg = Wt + (size_t)(col0 + wave * 32 + (lane >> 3)) * Kk + (lane & 7) * 8;
    us* Ad = &As[(wave * 4) * 512];
    us* Bd = &Bs[(wave * 4) * 512];

    for (int k0 = 0; k0 < Kk; k0 += 64) {
        __syncthreads();
#pragma unroll
        for (int i = 0; i < 4; ++i) {
            gload16(Ad + i * 512, Ag + (size_t)(i * 8) * Kk + k0);
            gload16(Bd + i * 512, Bg + (size_t)(i * 8) * Kk + k0);
        }
        __syncthreads();
#pragma unroll
        for (int ks = 0; ks < 2; ++ks) {
            bf16x8 af[4], bfr[4];
#pragma unroll
            for (int mt = 0; mt < 4; ++mt)
                af[mt] = *(const bf16x8*)&As[(wr * 64 + mt * 16 + ll) * 64 + ks * 32 + lg * 8];
#pragma unroll
            for (int nt = 0; nt < 4; ++nt)
                bfr[nt] = *(const bf16x8*)&Bs[(wc * 64 + nt * 16 + ll) * 64 + ks * 32 + lg * 8];
#pragma unroll
            for (int mt = 0; mt < 4; ++mt)
#pragma unroll
                for (int nt = 0; nt < 4; ++nt)
                    acc[mt][nt] = __builtin_amdgcn_mfma_f32_16x16x32_bf16(af[mt], bfr[nt], acc[mt][nt], 0, 0, 0);
        }
    }

    const int z = col0 >> 10;
    const int c0 = col0 & 1023;
    const float* bias = (z == 0) ? bq : (z == 1) ? bk : bv;
    const float osc = (z == 0) ? 0.125f : 1.0f;   // fold 1/sqrt(DH) into Q
    us* outz = QKV + (size_t)z * Mm * Dd;

    if (z == 2) {
#pragma unroll
        for (int mt = 0; mt < 4; ++mt)
#pragma unroll
            for (int nt = 0; nt < 4; ++nt) {
                int row = row0 + wr * 64 + mt * 16 + lg * 4;
                int col = c0 + wc * 64 + nt * 16 + ll;
                int b_ = row >> 11, s_ = row & 2047;
                float bv_ = bias[col];
                union { us u[4]; uint2 d2; } pk;
#pragma unroll
                for (int r = 0; r < 4; ++r) pk.u[r] = (us)f2b(acc[mt][nt][r] + bv_);
                *(uint2*)&outz[((size_t)(b_ * Hh * DHh) + col) * Ss + s_] = pk.d2;
            }
    } else {
#pragma unroll
        for (int mt = 0; mt < 4; ++mt)
#pragma unroll
            for (int nt = 0; nt < 4; ++nt)
#pragma unroll
                for (int r = 0; r < 4; ++r) {
                    int row = row0 + wr * 64 + mt * 16 + lg * 4 + r;
                    int col = c0 + wc * 64 + nt * 16 + ll;
                    float v = (acc[mt][nt][r] + bias[col]) * osc;
                    int b_ = row >> 11, s_ = row & 2047, h_ = col >> 6, d_ = col & 63;
                    outz[(((size_t)(b_ * Hh + h_)) * Ss + s_) * DHh + d_] = (us)f2b(v);
                }
    }
}

// ---- final GEMM, split-bf16, m97 structure ----
__global__ __launch_bounds__(256)
void gemm_final_kernel(const us* __restrict__ Oh, const us* __restrict__ Ol,
                       const us* __restrict__ Wth, const us* __restrict__ Wtl,
                       const float* __restrict__ bo, float* __restrict__ out)
{
    __shared__ us AhS[128 * 64];
    __shared__ us AlS[128 * 64];
    __shared__ us BhS[64 * 64];
    __shared__ us BlS[64 * 64];
    const int tid = threadIdx.x;
    const int wave = tid >> 6, lane = tid & 63;
    const int wr = wave >> 1, wc = wave & 1;
    const int lg = lane >> 4, ll = lane & 15;
    const int col0 = blockIdx.x * 64;
    const int row0 = blockIdx.y * 128;

    f32x4 acc[4][2];
#pragma unroll
    for (int mt = 0; mt < 4; ++mt)
#pragma unroll
        for (int nt = 0; nt < 2; ++nt)
#pragma unroll
            for (int r = 0; r < 4; ++r) acc[mt][nt][r] = 0.f;

    const size_t aoff = (size_t)(row0 + wave * 32 + (lane >> 3)) * Kk + (lane & 7) * 8;
    const size_t boff = (size_t)(col0 + wave * 16 + (lane >> 3)) * Kk + (lane & 7) * 8;
    const us* Ahg = Oh + aoff;
    const us* Alg = Ol + aoff;
    const us* Bhg = Wth + boff;
    const us* Blg = Wtl + boff;
    us* AhD = &AhS[(wave * 4) * 512];
    us* AlD = &AlS[(wave * 4) * 512];
    us* BhD = &BhS[(wave * 2) * 512];
    us* BlD = &BlS[(wave * 2) * 512];

    for (int k0 = 0; k0 < Kk; k0 += 64) {
        __syncthreads();
#pragma unroll
        for (int i = 0; i < 4; ++i) {
            gload16(AhD + i * 512, Ahg + (size_t)(i * 8) * Kk + k0);
            gload16(AlD + i * 512, Alg + (size_t)(i * 8) * Kk + k0);
        }
#pragma unroll
        for (int j = 0; j < 2; ++j) {
            gload16(BhD + j * 512, Bhg + (size_t)(j * 8) * Kk + k0);
            gload16(BlD + j * 512, Blg + (size_t)(j * 8) * Kk + k0);
        }
        __syncthreads();
#pragma unroll
        for (int ks = 0; ks < 2; ++ks) {
            bf16x8 ah[4], al[4], bh[2], bl[2];
#pragma unroll
            for (int mt = 0; mt < 4; ++mt) {
                ah[mt] = *(const bf16x8*)&AhS[(wr * 64 + mt * 16 + ll) * 64 + ks * 32 + lg * 8];
                al[mt] = *(const bf16x8*)&AlS[(wr * 64 + mt * 16 + ll) * 64 + ks * 32 + lg * 8];
            }
#pragma unroll
            for (int nt = 0; nt < 2; ++nt) {
                bh[nt] = *(const bf16x8*)&BhS[(wc * 32 + nt * 16 + ll) * 64 + ks * 32 + lg * 8];
                bl[nt] = *(const bf16x8*)&BlS[(wc * 32 + nt * 16 + ll) * 64 + ks * 32 + lg * 8];
            }
#pragma unroll
            for (int mt = 0; mt < 4; ++mt)
#pragma unroll
                for (int nt = 0; nt < 2; ++nt) {
                    acc[mt][nt] = __builtin_amdgcn_mfma_f32_16x16x32_bf16(ah[mt], bh[nt], acc[mt][nt], 0, 0, 0);
                    acc[mt][nt] = __builtin_amdgcn_mfma_f32_16x16x32_bf16(al[mt], bh[nt], acc[mt][nt], 0, 0, 0);
                    acc[mt][nt] = __builtin_amdgcn_mfma_f32_16x16x32_bf16(ah[mt], bl[nt], acc[mt][nt], 0, 0, 0);
                }
        }
    }

#pragma unroll
    for (int mt = 0; mt < 4; ++mt)
#pragma unroll
        for (int nt = 0; nt < 2; ++nt)
#pragma unroll
            for (int r = 0; r < 4; ++r) {
                int row = row0 + wr * 64 + mt * 16 + lg * 4 + r;
                int col = col0 + wc * 32 + nt * 16 + ll;
                out[(size_t)row * Dd + col] = acc[mt][nt][r] + bo[col];
            }
}

// ---- Flash attention: pre-scaled Q, boundary-only mask, defer-max,
//      row-sums via ones-column MFMA ----
__global__ __launch_bounds__(256)
void attn_mfma_kernel(const us* __restrict__ Q, const us* __restrict__ K,
                      const us* __restrict__ Vt_g, const int* __restrict__ valid_nums,
                      us* __restrict__ Oh, us* __restrict__ Ol)
{
    const int bh = blockIdx.y;
    const int b  = bh >> 4, h = bh & 15;
    const int q0 = blockIdx.x * 64;
    const int tid  = threadIdx.x;
    const int wave = tid >> 6;
    const int lane = tid & 63;
    const int lg = lane >> 4;
    const int ll = lane & 15;

    const int nv = valid_nums[b];
    const int ntiles = (nv + 63) >> 6;

    const us* Qb = Q    + (size_t)bh * Ss * DHh;
    const us* Kb = K    + (size_t)bh * Ss * DHh;
    const us* Vb = Vt_g + (size_t)bh * DHh * Ss;   // [d][s]

    __shared__ us Ks[64][68];
    __shared__ us Vs[64][68];

    bf16x8 qa[2];
    {
        const us* qrow = Qb + (size_t)(q0 + wave * 16 + ll) * DHh;
        qa[0] = *(const bf16x8*)(qrow + lg * 8);
        qa[1] = *(const bf16x8*)(qrow + 32 + lg * 8);
    }

    // ones B-fragment (bf16 1.0 = 0x3F80) for MFMA row-sums
    union { unsigned w[4]; bf16x8 v; } ones_u;
#pragma unroll
    for (int i = 0; i < 4; ++i) ones_u.w[i] = 0x3F803F80u;
    const bf16x8 vones = ones_u.v;

    f32x4 o[4], o4;
#pragma unroll
    for (int nt = 0; nt < 4; ++nt) { o[nt][0]=0.f; o[nt][1]=0.f; o[nt][2]=0.f; o[nt][3]=0.f; }
    o4[0]=0.f; o4[1]=0.f; o4[2]=0.f; o4[3]=0.f;
    float mq = -INFINITY;                     // per-lane running max for q = ll

    const int srow = tid >> 2;
    const int scol = (tid & 3) * 16;

    for (int kt = 0; kt < ntiles; ++kt) {
        const int k0 = kt * 64;
        __syncthreads();
        {
            const us* Kr = Kb + (size_t)(k0 + srow) * DHh + scol;
            *(bf16x8*)&Ks[srow][scol]     = *(const bf16x8*)Kr;
            *(bf16x8*)&Ks[srow][scol + 8] = *(const bf16x8*)(Kr + 8);
            const us* Vr = Vb + (size_t)srow * Ss + k0 + scol;
            *(bf16x8*)&Vs[srow][scol]     = *(const bf16x8*)Vr;
            *(bf16x8*)&Vs[srow][scol + 8] = *(const bf16x8*)(Vr + 8);
        }
        __syncthreads();

        // S^T = K Q^T (Q pre-scaled): s[nt][r] = S[key=k0+nt*16+lg*4+r][q=ll]
        f32x4 s[4];
#pragma unroll
        for (int nt = 0; nt < 4; ++nt) { s[nt][0]=0.f; s[nt][1]=0.f; s[nt][2]=0.f; s[nt][3]=0.f; }
#pragma unroll
        for (int ks = 0; ks < 2; ++ks) {
#pragma unroll
            for (int nt = 0; nt < 4; ++nt) {
                bf16x8 kf = *(const bf16x8*)&Ks[nt * 16 + ll][ks * 32 + lg * 8];
                s[nt] = __builtin_amdgcn_mfma_f32_16x16x32_bf16(kf, qa[ks], s[nt], 0, 0, 0);
            }
        }

        float p[4][4];
        float mx;
        if (k0 + 64 <= nv) {                  // interior tile: no masking
#pragma unroll
            for (int nt = 0; nt < 4; ++nt)
#pragma unroll
                for (int r = 0; r < 4; ++r) p[nt][r] = s[nt][r];
            mx = fmaxf(fmaxf(fmaxf(p[0][0], p[0][1]), fmaxf(p[0][2], p[0][3])),
                       fmaxf(fmaxf(p[1][0], p[1][1]), fmaxf(p[1][2], p[1][3])));
            mx = fmaxf(mx,
                 fmaxf(fmaxf(fmaxf(p[2][0], p[2][1]), fmaxf(p[2][2], p[2][3])),
                       fmaxf(fmaxf(p[3][0], p[3][1]), fmaxf(p[3][2], p[3][3]))));
        } else {                              // boundary tile
            mx = -INFINITY;
#pragma unroll
            for (int nt = 0; nt < 4; ++nt)
#pragma unroll
                for (int r = 0; r < 4; ++r) {
                    int key = k0 + nt * 16 + lg * 4 + r;
                    float v = (key < nv) ? s[nt][r] : -INFINITY;
                    p[nt][r] = v;
                    mx = fmaxf(mx, v);
                }
        }
        mx = fmaxf(mx, __shfl_xor(mx, 16));
        mx = fmaxf(mx, __shfl_xor(mx, 32));

        // defer-max: skip rescale while max growth <= 8 (P bounded by e^8)
        const bool rescale = !__all(mx <= mq + 8.f);
        if (rescale) {
            float mn = fmaxf(mq, mx);
            float corr = __expf(mq - mn);     // mq=-inf -> 0
            mq = mn;
            float corr4[4];
#pragma unroll
            for (int r = 0; r < 4; ++r) corr4[r] = __shfl(corr, lg * 16 + lg * 4 + r);
#pragma unroll
            for (int nt = 0; nt < 4; ++nt)
#pragma unroll
                for (int r = 0; r < 4; ++r) o[nt][r] *= corr4[r];
#pragma unroll
            for (int r = 0; r < 4; ++r) o4[r] *= corr4[r];
        }

#pragma unroll
        for (int nt = 0; nt < 4; ++nt)
#pragma unroll
            for (int r = 0; r < 4; ++r) p[nt][r] = __expf(p[nt][r] - mq);

        unsigned dw[4][2];
#pragma unroll
        for (int nt = 0; nt < 4; ++nt) {
            dw[nt][0] = pk2(p[nt][0], p[nt][1]);
            dw[nt][1] = pk2(p[nt][2], p[nt][3]);
        }

        // route P into A-fragments via lane gather, then O += P V, o4 += P 1
        const int sA = ((2 * lg) & 3) * 16 + ll;
        const int sB = ((2 * lg + 1) & 3) * 16 + ll;
        const bool hi = (lg & 2);
#pragma unroll
        for (int ks = 0; ks < 2; ++ks) {
            unsigned a0 = (unsigned)__shfl((int)dw[2 * ks][0],     sA);
            unsigned a1 = (unsigned)__shfl((int)dw[2 * ks][1],     sA);
            unsigned a2 = (unsigned)__shfl((int)dw[2 * ks][0],     sB);
            unsigned a3 = (unsigned)__shfl((int)dw[2 * ks][1],     sB);
            unsigned b0 = (unsigned)__shfl((int)dw[2 * ks + 1][0], sA);
            unsigned b1 = (unsigned)__shfl((int)dw[2 * ks + 1][1], sA);
            unsigned b2 = (unsigned)__shfl((int)dw[2 * ks + 1][0], sB);
            unsigned b3 = (unsigned)__shfl((int)dw[2 * ks + 1][1], sB);
            union { unsigned w[4]; bf16x8 v; } pa;
            pa.w[0] = hi ? b0 : a0;
            pa.w[1] = hi ? b1 : a1;
            pa.w[2] = hi ? b2 : a2;
            pa.w[3] = hi ? b3 : a3;
#pragma unroll
            for (int nt = 0; nt < 4; ++nt) {
                bf16x8 vb = *(const bf16x8*)&Vs[nt * 16 + ll][ks * 32 + lg * 8];
                o[nt] = __builtin_amdgcn_mfma_f32_16x16x32_bf16(pa.v, vb, o[nt], 0, 0, 0);
            }
            o4 = __builtin_amdgcn_mfma_f32_16x16x32_bf16(pa.v, vones, o4, 0, 0, 0);
        }
    }

    // epilogue: o4[r] = sum_k P[q=lg*4+r][k] (replicated over ll)
#pragma unroll
    for (int r = 0; r < 4; ++r) {
        int row = q0 + wave * 16 + lg * 4 + r;
        float linv = 1.f / o4[r];
#pragma unroll
        for (int nt = 0; nt < 4; ++nt) {
            float val = o[nt][r] * linv;
            us uh = (us)f2b(val);
            float rem = val - b2f(uh);
            size_t base = ((size_t)b * Ss + row) * Dd + h * DHh + nt * 16 + ll;
            Oh[base] = uh;
            Ol[base] = (us)f2b(rem);
        }
    }
}

extern "C" void kernel_launch(void* const* d_in, const int* in_sizes, int n_in,
                              void* d_out, int out_size, void* d_ws, size_t ws_size,
                              hipStream_t stream) {
    const float* x     = (const float*)d_in[0];
    const int*   valid = (const int*)d_in[1];
    const float* Wq = (const float*)d_in[2];
    const float* bq = (const float*)d_in[3];
    const float* Wk = (const float*)d_in[4];
    const float* bk = (const float*)d_in[5];
    const float* Wv = (const float*)d_in[6];
    const float* bv = (const float*)d_in[7];
    const float* Wo = (const float*)d_in[8];
    const float* bo = (const float*)d_in[9];

    const size_t per = (size_t)Mm * Dd;      // 4,194,304
    const size_t wsz = (size_t)Dd * Kk;      // 1,048,576
    us* wsp  = (us*)d_ws;
    us* QKV  = wsp;                // 3*per  (Q,K natural; V transposed)
    us* Wt   = QKV + 3 * per;      // 3*wsz
    us* OhB  = Wt + 3 * wsz;       // per
    us* OlB  = OhB + per;          // per
    us* Woth = OlB + per;          // wsz
    us* Wotl = Woth + wsz;         // wsz
    us* xb   = Wotl + wsz;         // per

    xconv_kernel<<<(Mm * Kk) / (256 * 8), 256, 0, stream>>>(x, xb);

    wtrans_kernel<<<dim3(Dd / 64, Kk / 64, 4), 256, 0, stream>>>(
        Wq, Wk, Wv, Wo, Wt, Woth, Wotl);

    gemm_qkv_kernel<<<dim3(3 * Dd / 128, Mm / 128), 256, 0, stream>>>(
        xb, Wt, bq, bk, bv, QKV);

    attn_mfma_kernel<<<dim3(Ss / 64, Bb * Hh), 256, 0, stream>>>(
        QKV, QKV + per, QKV + 2 * per, valid, OhB, OlB);

    gemm_final_kernel<<<dim3(Dd / 64, Mm / 128), 256, 0, stream>>>(
        OhB, OlB, Woth, Wotl, bo, (float*)d_out);
}

// Round 8
// 145.750 us; speedup vs baseline: 35.5495x; 1.0644x over previous
//
#include <hip/hip_runtime.h>
#include <hip/hip_bf16.h>
#include <math.h>

static constexpr int Bb = 2, Ss = 2048, Dd = 1024, Hh = 16, DHh = 64;
static constexpr int Mm = Bb * Ss;     // 4096
static constexpr int Kk = Dd;          // 1024

typedef __attribute__((ext_vector_type(8))) short bf16x8;
typedef __attribute__((ext_vector_type(4))) float f32x4;
typedef unsigned short us;

__device__ inline short f2b(float f) {
    __hip_bfloat16 h = __float2bfloat16(f);
    return *reinterpret_cast<short*>(&h);
}
__device__ inline float b2f(us u) {
    __hip_bfloat16 h = *reinterpret_cast<__hip_bfloat16*>(&u);
    return __bfloat162float(h);
}
__device__ inline unsigned pk2(float lo, float hi) {
    return ((unsigned)(us)f2b(hi) << 16) | (unsigned)(us)f2b(lo);
}
__device__ inline float ex2(float x) {           // 2^x via v_exp_f32
    return __builtin_amdgcn_exp2f(x);
}

// async global->LDS, 16B per lane; dst is wave-uniform base (HW adds lane*16)
__device__ inline void gload16(us* lds, const us* g) {
    __builtin_amdgcn_global_load_lds(
        (const __attribute__((address_space(1))) void*)g,
        (__attribute__((address_space(3))) void*)lds,
        16, 0, 0);
}

// ---- x fp32 -> bf16 ----
__global__ __launch_bounds__(256)
void xconv_kernel(const float* __restrict__ x, us* __restrict__ xb)
{
    const size_t i = ((size_t)blockIdx.x * 256 + threadIdx.x) * 8;
    float4 a = *(const float4*)(x + i);
    float4 b = *(const float4*)(x + i + 4);
    bf16x8 t;
    t[0] = f2b(a.x); t[1] = f2b(a.y); t[2] = f2b(a.z); t[3] = f2b(a.w);
    t[4] = f2b(b.x); t[5] = f2b(b.y); t[6] = f2b(b.z); t[7] = f2b(b.w);
    *(bf16x8*)(xb + i) = t;
}

// ---- fused transpose+convert for all 4 weights (z=0..3); z==3 hi/lo split ----
__global__ __launch_bounds__(256)
void wtrans_kernel(const float* __restrict__ Wq, const float* __restrict__ Wk,
                   const float* __restrict__ Wv, const float* __restrict__ Wo,
                   us* __restrict__ Wt, us* __restrict__ Woth, us* __restrict__ Wotl)
{
    __shared__ float T[64][65];
    const int z = blockIdx.z;
    const float* W = (z == 0) ? Wq : (z == 1) ? Wk : (z == 2) ? Wv : Wo;
    const int split = (z == 3);
    us* dh = split ? Woth : (Wt + (size_t)z * Dd * Kk);
    us* dl = Wotl;

    const int n0 = blockIdx.x * 64, k0 = blockIdx.y * 64;
    const int tid = threadIdx.x;
    const int r = tid >> 2, c0 = (tid & 3) * 16;
#pragma unroll
    for (int j = 0; j < 4; ++j) {
        float4 v = *(const float4*)(W + (size_t)(k0 + r) * Dd + n0 + c0 + 4 * j);
        T[r][c0 + 4 * j + 0] = v.x;
        T[r][c0 + 4 * j + 1] = v.y;
        T[r][c0 + 4 * j + 2] = v.z;
        T[r][c0 + 4 * j + 3] = v.w;
    }
    __syncthreads();
    us hi[16], lo[16];
#pragma unroll
    for (int j = 0; j < 16; ++j) {
        float v = T[c0 + j][r];
        us h = (us)f2b(v);
        hi[j] = h;
        if (split) lo[j] = (us)f2b(v - b2f(h));
    }
    *(bf16x8*)&dh[(size_t)(n0 + r) * Kk + k0 + c0]     = *(bf16x8*)&hi[0];
    *(bf16x8*)&dh[(size_t)(n0 + r) * Kk + k0 + c0 + 8] = *(bf16x8*)&hi[8];
    if (split) {
        *(bf16x8*)&dl[(size_t)(n0 + r) * Kk + k0 + c0]     = *(bf16x8*)&lo[0];
        *(bf16x8*)&dl[(size_t)(n0 + r) * Kk + k0 + c0 + 8] = *(bf16x8*)&lo[8];
    }
}

// ---- fused QKV GEMM, m97 structure. Q pre-scaled by log2(e)/sqrt(DH). ----
__global__ __launch_bounds__(256)
void gemm_qkv_kernel(const us* __restrict__ xb, const us* __restrict__ Wt,
                     const float* __restrict__ bq, const float* __restrict__ bk,
                     const float* __restrict__ bv, us* __restrict__ QKV)
{
    __shared__ us As[128 * 64];
    __shared__ us Bs[128 * 64];
    const int tid = threadIdx.x;
    const int wave = tid >> 6, lane = tid & 63;
    const int wr = wave >> 1, wc = wave & 1;
    const int lg = lane >> 4, ll = lane & 15;
    const int col0 = blockIdx.x * 128;           // 0..3071
    const int row0 = blockIdx.y * 128;

    f32x4 acc[4][4];
#pragma unroll
    for (int mt = 0; mt < 4; ++mt)
#pragma unroll
        for (int nt = 0; nt < 4; ++nt)
#pragma unroll
            for (int r = 0; r < 4; ++r) acc[mt][nt][r] = 0.f;

    const us* Ag = xb + (size_t)(row0 + wave * 32 + (lane >> 3)) * Kk + (lane & 7) * 8;
    const us* Bg = Wt + (size_t)(col0 + wave * 32 + (lane >> 3)) * Kk + (lane & 7) * 8;
    us* Ad = &As[(wave * 4) * 512];
    us* Bd = &Bs[(wave * 4) * 512];

    for (int k0 = 0; k0 < Kk; k0 += 64) {
        __syncthreads();
#pragma unroll
        for (int i = 0; i < 4; ++i) {
            gload16(Ad + i * 512, Ag + (size_t)(i * 8) * Kk + k0);
            gload16(Bd + i * 512, Bg + (size_t)(i * 8) * Kk + k0);
        }
        __syncthreads();
#pragma unroll
        for (int ks = 0; ks < 2; ++ks) {
            bf16x8 af[4], bfr[4];
#pragma unroll
            for (int mt = 0; mt < 4; ++mt)
                af[mt] = *(const bf16x8*)&As[(wr * 64 + mt * 16 + ll) * 64 + ks * 32 + lg * 8];
#pragma unroll
            for (int nt = 0; nt < 4; ++nt)
                bfr[nt] = *(const bf16x8*)&Bs[(wc * 64 + nt * 16 + ll) * 64 + ks * 32 + lg * 8];
#pragma unroll
            for (int mt = 0; mt < 4; ++mt)
#pragma unroll
                for (int nt = 0; nt < 4; ++nt)
                    acc[mt][nt] = __builtin_amdgcn_mfma_f32_16x16x32_bf16(af[mt], bfr[nt], acc[mt][nt], 0, 0, 0);
        }
    }

    const int z = col0 >> 10;
    const int c0 = col0 & 1023;
    const float* bias = (z == 0) ? bq : (z == 1) ? bk : bv;
    // fold 1/sqrt(DH) * log2(e) into Q so softmax runs in exp2 domain
    const float osc = (z == 0) ? 0.125f * 1.44269504f : 1.0f;
    us* outz = QKV + (size_t)z * Mm * Dd;

    if (z == 2) {
#pragma unroll
        for (int mt = 0; mt < 4; ++mt)
#pragma unroll
            for (int nt = 0; nt < 4; ++nt) {
                int row = row0 + wr * 64 + mt * 16 + lg * 4;
                int col = c0 + wc * 64 + nt * 16 + ll;
                int b_ = row >> 11, s_ = row & 2047;
                float bv_ = bias[col];
                union { us u[4]; uint2 d2; } pk;
#pragma unroll
                for (int r = 0; r < 4; ++r) pk.u[r] = (us)f2b(acc[mt][nt][r] + bv_);
                *(uint2*)&outz[((size_t)(b_ * Hh * DHh) + col) * Ss + s_] = pk.d2;
            }
    } else {
#pragma unroll
        for (int mt = 0; mt < 4; ++mt)
#pragma unroll
            for (int nt = 0; nt < 4; ++nt)
#pragma unroll
                for (int r = 0; r < 4; ++r) {
                    int row = row0 + wr * 64 + mt * 16 + lg * 4 + r;
                    int col = c0 + wc * 64 + nt * 16 + ll;
                    float v = (acc[mt][nt][r] + bias[col]) * osc;
                    int b_ = row >> 11, s_ = row & 2047, h_ = col >> 6, d_ = col & 63;
                    outz[(((size_t)(b_ * Hh + h_)) * Ss + s_) * DHh + d_] = (us)f2b(v);
                }
    }
}

// ---- final GEMM, split-bf16, m97 structure ----
__global__ __launch_bounds__(256)
void gemm_final_kernel(const us* __restrict__ Oh, const us* __restrict__ Ol,
                       const us* __restrict__ Wth, const us* __restrict__ Wtl,
                       const float* __restrict__ bo, float* __restrict__ out)
{
    __shared__ us AhS[128 * 64];
    __shared__ us AlS[128 * 64];
    __shared__ us BhS[64 * 64];
    __shared__ us BlS[64 * 64];
    const int tid = threadIdx.x;
    const int wave = tid >> 6, lane = tid & 63;
    const int wr = wave >> 1, wc = wave & 1;
    const int lg = lane >> 4, ll = lane & 15;
    const int col0 = blockIdx.x * 64;
    const int row0 = blockIdx.y * 128;

    f32x4 acc[4][2];
#pragma unroll
    for (int mt = 0; mt < 4; ++mt)
#pragma unroll
        for (int nt = 0; nt < 2; ++nt)
#pragma unroll
            for (int r = 0; r < 4; ++r) acc[mt][nt][r] = 0.f;

    const size_t aoff = (size_t)(row0 + wave * 32 + (lane >> 3)) * Kk + (lane & 7) * 8;
    const size_t boff = (size_t)(col0 + wave * 16 + (lane >> 3)) * Kk + (lane & 7) * 8;
    const us* Ahg = Oh + aoff;
    const us* Alg = Ol + aoff;
    const us* Bhg = Wth + boff;
    const us* Blg = Wtl + boff;
    us* AhD = &AhS[(wave * 4) * 512];
    us* AlD = &AlS[(wave * 4) * 512];
    us* BhD = &BhS[(wave * 2) * 512];
    us* BlD = &BlS[(wave * 2) * 512];

    for (int k0 = 0; k0 < Kk; k0 += 64) {
        __syncthreads();
#pragma unroll
        for (int i = 0; i < 4; ++i) {
            gload16(AhD + i * 512, Ahg + (size_t)(i * 8) * Kk + k0);
            gload16(AlD + i * 512, Alg + (size_t)(i * 8) * Kk + k0);
        }
#pragma unroll
        for (int j = 0; j < 2; ++j) {
            gload16(BhD + j * 512, Bhg + (size_t)(j * 8) * Kk + k0);
            gload16(BlD + j * 512, Blg + (size_t)(j * 8) * Kk + k0);
        }
        __syncthreads();
#pragma unroll
        for (int ks = 0; ks < 2; ++ks) {
            bf16x8 ah[4], al[4], bh[2], bl[2];
#pragma unroll
            for (int mt = 0; mt < 4; ++mt) {
                ah[mt] = *(const bf16x8*)&AhS[(wr * 64 + mt * 16 + ll) * 64 + ks * 32 + lg * 8];
                al[mt] = *(const bf16x8*)&AlS[(wr * 64 + mt * 16 + ll) * 64 + ks * 32 + lg * 8];
            }
#pragma unroll
            for (int nt = 0; nt < 2; ++nt) {
                bh[nt] = *(const bf16x8*)&BhS[(wc * 32 + nt * 16 + ll) * 64 + ks * 32 + lg * 8];
                bl[nt] = *(const bf16x8*)&BlS[(wc * 32 + nt * 16 + ll) * 64 + ks * 32 + lg * 8];
            }
#pragma unroll
            for (int mt = 0; mt < 4; ++mt)
#pragma unroll
                for (int nt = 0; nt < 2; ++nt) {
                    acc[mt][nt] = __builtin_amdgcn_mfma_f32_16x16x32_bf16(ah[mt], bh[nt], acc[mt][nt], 0, 0, 0);
                    acc[mt][nt] = __builtin_amdgcn_mfma_f32_16x16x32_bf16(al[mt], bh[nt], acc[mt][nt], 0, 0, 0);
                    acc[mt][nt] = __builtin_amdgcn_mfma_f32_16x16x32_bf16(ah[mt], bl[nt], acc[mt][nt], 0, 0, 0);
                }
        }
    }

#pragma unroll
    for (int mt = 0; mt < 4; ++mt)
#pragma unroll
        for (int nt = 0; nt < 2; ++nt)
#pragma unroll
            for (int r = 0; r < 4; ++r) {
                int row = row0 + wr * 64 + mt * 16 + lg * 4 + r;
                int col = col0 + wc * 32 + nt * 16 + ll;
                out[(size_t)row * Dd + col] = acc[mt][nt][r] + bo[col];
            }
}

// ---- Flash attention: QBLK=128 x 8 waves, T14 async staging, exp2 domain,
//      boundary-only mask, defer-max, ones-column MFMA row-sums, XCD swizzle ----
__global__ __launch_bounds__(512)
void attn_mfma_kernel(const us* __restrict__ Q, const us* __restrict__ K,
                      const us* __restrict__ Vt_g, const int* __restrict__ valid_nums,
                      us* __restrict__ Oh, us* __restrict__ Ol)
{
    // XCD-aware swizzle: XCD = flat%8 gets bh {xcd, xcd+8, xcd+16, xcd+24}
    // (balanced across both batches) x all 16 q-blocks -> 2 MB K/V per L2.
    const int id  = blockIdx.x;               // 0..511
    const int xcd = id & 7, grp = id >> 3;    // grp 0..63
    const int bh  = (grp >> 4) * 8 + xcd;     // 0..31
    const int qb  = grp & 15;
    const int b   = bh >> 4, h = bh & 15;
    const int q0  = qb * 128;

    const int tid  = threadIdx.x;
    const int wave = tid >> 6;                // 0..7
    const int lane = tid & 63;
    const int lg = lane >> 4;
    const int ll = lane & 15;

    const int nv = valid_nums[b];
    const int ntiles = (nv + 63) >> 6;

    const us* Qb = Q    + (size_t)bh * Ss * DHh;
    const us* Kb = K    + (size_t)bh * Ss * DHh;
    const us* Vb = Vt_g + (size_t)bh * DHh * Ss;   // [d][s]

    __shared__ us Ks[64][68];
    __shared__ us Vs[64][68];

    bf16x8 qa[2];
    {
        const us* qrow = Qb + (size_t)(q0 + wave * 16 + ll) * DHh;
        qa[0] = *(const bf16x8*)(qrow + lg * 8);
        qa[1] = *(const bf16x8*)(qrow + 32 + lg * 8);
    }

    // ones B-fragment (bf16 1.0 = 0x3F80) for MFMA row-sums
    union { unsigned w[4]; bf16x8 v; } ones_u;
#pragma unroll
    for (int i = 0; i < 4; ++i) ones_u.w[i] = 0x3F803F80u;
    const bf16x8 vones = ones_u.v;

    f32x4 o[4], o4;
#pragma unroll
    for (int nt = 0; nt < 4; ++nt) { o[nt][0]=0.f; o[nt][1]=0.f; o[nt][2]=0.f; o[nt][3]=0.f; }
    o4[0]=0.f; o4[1]=0.f; o4[2]=0.f; o4[3]=0.f;
    float mq = -INFINITY;                     // per-lane running max (log2 units), q = ll

    // staging: 512 threads x 16B cover one 64x64 bf16 tile
    const int srow = tid >> 3;                // 0..63
    const int scol = (tid & 7) * 8;           // 0..56

    bf16x8 kreg = *(const bf16x8*)(Kb + (size_t)srow * DHh + scol);
    bf16x8 vreg = *(const bf16x8*)(Vb + (size_t)srow * Ss + scol);

    for (int kt = 0; kt < ntiles; ++kt) {
        const int k0 = kt * 64;
        __syncthreads();                      // previous tile consumed
        *(bf16x8*)&Ks[srow][scol] = kreg;
        *(bf16x8*)&Vs[srow][scol] = vreg;
        __syncthreads();                      // tile ready
        if (kt + 1 < ntiles) {                // T14: issue next loads early
            kreg = *(const bf16x8*)(Kb + (size_t)(k0 + 64 + srow) * DHh + scol);
            vreg = *(const bf16x8*)(Vb + (size_t)srow * Ss + k0 + 64 + scol);
        }

        // S^T = K Q^T (Q pre-scaled into log2 units)
        f32x4 s[4];
#pragma unroll
        for (int nt = 0; nt < 4; ++nt) { s[nt][0]=0.f; s[nt][1]=0.f; s[nt][2]=0.f; s[nt][3]=0.f; }
#pragma unroll
        for (int ks = 0; ks < 2; ++ks) {
#pragma unroll
            for (int nt = 0; nt < 4; ++nt) {
                bf16x8 kf = *(const bf16x8*)&Ks[nt * 16 + ll][ks * 32 + lg * 8];
                s[nt] = __builtin_amdgcn_mfma_f32_16x16x32_bf16(kf, qa[ks], s[nt], 0, 0, 0);
            }
        }

        float p[4][4];
        float mx;
        if (k0 + 64 <= nv) {                  // interior tile: no masking
#pragma unroll
            for (int nt = 0; nt < 4; ++nt)
#pragma unroll
                for (int r = 0; r < 4; ++r) p[nt][r] = s[nt][r];
            mx = fmaxf(fmaxf(fmaxf(p[0][0], p[0][1]), fmaxf(p[0][2], p[0][3])),
                       fmaxf(fmaxf(p[1][0], p[1][1]), fmaxf(p[1][2], p[1][3])));
            mx = fmaxf(mx,
                 fmaxf(fmaxf(fmaxf(p[2][0], p[2][1]), fmaxf(p[2][2], p[2][3])),
                       fmaxf(fmaxf(p[3][0], p[3][1]), fmaxf(p[3][2], p[3][3]))));
        } else {                              // boundary tile
            mx = -INFINITY;
#pragma unroll
            for (int nt = 0; nt < 4; ++nt)
#pragma unroll
                for (int r = 0; r < 4; ++r) {
                    int key = k0 + nt * 16 + lg * 4 + r;
                    float v = (key < nv) ? s[nt][r] : -INFINITY;
                    p[nt][r] = v;
                    mx = fmaxf(mx, v);
                }
        }
        mx = fmaxf(mx, __shfl_xor(mx, 16));
        mx = fmaxf(mx, __shfl_xor(mx, 32));

        // defer-max: skip rescale while growth <= 8*log2e (P bounded by e^8)
        const bool rescale = !__all(mx <= mq + 11.5f);
        if (rescale) {
            float mn = fmaxf(mq, mx);
            float corr = ex2(mq - mn);        // mq=-inf -> 0
            mq = mn;
            float corr4[4];
#pragma unroll
            for (int r = 0; r < 4; ++r) corr4[r] = __shfl(corr, lg * 16 + lg * 4 + r);
#pragma unroll
            for (int nt = 0; nt < 4; ++nt)
#pragma unroll
                for (int r = 0; r < 4; ++r) o[nt][r] *= corr4[r];
#pragma unroll
            for (int r = 0; r < 4; ++r) o4[r] *= corr4[r];
        }

#pragma unroll
        for (int nt = 0; nt < 4; ++nt)
#pragma unroll
            for (int r = 0; r < 4; ++r) p[nt][r] = ex2(p[nt][r] - mq);

        unsigned dw[4][2];
#pragma unroll
        for (int nt = 0; nt < 4; ++nt) {
            dw[nt][0] = pk2(p[nt][0], p[nt][1]);
            dw[nt][1] = pk2(p[nt][2], p[nt][3]);
        }

        // route P into A-fragments via lane gather, then O += P V, o4 += P 1
        const int sA = ((2 * lg) & 3) * 16 + ll;
        const int sB = ((2 * lg + 1) & 3) * 16 + ll;
        const bool hi = (lg & 2);
#pragma unroll
        for (int ks = 0; ks < 2; ++ks) {
            unsigned a0 = (unsigned)__shfl((int)dw[2 * ks][0],     sA);
            unsigned a1 = (unsigned)__shfl((int)dw[2 * ks][1],     sA);
            unsigned a2 = (unsigned)__shfl((int)dw[2 * ks][0],     sB);
            unsigned a3 = (unsigned)__shfl((int)dw[2 * ks][1],     sB);
            unsigned b0 = (unsigned)__shfl((int)dw[2 * ks + 1][0], sA);
            unsigned b1 = (unsigned)__shfl((int)dw[2 * ks + 1][1], sA);
            unsigned b2 = (unsigned)__shfl((int)dw[2 * ks + 1][0], sB);
            unsigned b3 = (unsigned)__shfl((int)dw[2 * ks + 1][1], sB);
            union { unsigned w[4]; bf16x8 v; } pa;
            pa.w[0] = hi ? b0 : a0;
            pa.w[1] = hi ? b1 : a1;
            pa.w[2] = hi ? b2 : a2;
            pa.w[3] = hi ? b3 : a3;
#pragma unroll
            for (int nt = 0; nt < 4; ++nt) {
                bf16x8 vb = *(const bf16x8*)&Vs[nt * 16 + ll][ks * 32 + lg * 8];
                o[nt] = __builtin_amdgcn_mfma_f32_16x16x32_bf16(pa.v, vb, o[nt], 0, 0, 0);
            }
            o4 = __builtin_amdgcn_mfma_f32_16x16x32_bf16(pa.v, vones, o4, 0, 0, 0);
        }
    }

    // epilogue
#pragma unroll
    for (int r = 0; r < 4; ++r) {
        int row = q0 + wave * 16 + lg * 4 + r;
        float linv = 1.f / o4[r];
#pragma unroll
        for (int nt = 0; nt < 4; ++nt) {
            float val = o[nt][r] * linv;
            us uh = (us)f2b(val);
            float rem = val - b2f(uh);
            size_t base = ((size_t)b * Ss + row) * Dd + h * DHh + nt * 16 + ll;
            Oh[base] = uh;
            Ol[base] = (us)f2b(rem);
        }
    }
}

extern "C" void kernel_launch(void* const* d_in, const int* in_sizes, int n_in,
                              void* d_out, int out_size, void* d_ws, size_t ws_size,
                              hipStream_t stream) {
    const float* x     = (const float*)d_in[0];
    const int*   valid = (const int*)d_in[1];
    const float* Wq = (const float*)d_in[2];
    const float* bq = (const float*)d_in[3];
    const float* Wk = (const float*)d_in[4];
    const float* bk = (const float*)d_in[5];
    const float* Wv = (const float*)d_in[6];
    const float* bv = (const float*)d_in[7];
    const float* Wo = (const float*)d_in[8];
    const float* bo = (const float*)d_in[9];

    const size_t per = (size_t)Mm * Dd;      // 4,194,304
    const size_t wsz = (size_t)Dd * Kk;      // 1,048,576
    us* wsp  = (us*)d_ws;
    us* QKV  = wsp;                // 3*per  (Q,K natural; V transposed)
    us* Wt   = QKV + 3 * per;      // 3*wsz
    us* OhB  = Wt + 3 * wsz;       // per
    us* OlB  = OhB + per;          // per
    us* Woth = OlB + per;          // wsz
    us* Wotl = Woth + wsz;         // wsz
    us* xb   = Wotl + wsz;         // per

    xconv_kernel<<<(Mm * Kk) / (256 * 8), 256, 0, stream>>>(x, xb);

    wtrans_kernel<<<dim3(Dd / 64, Kk / 64, 4), 256, 0, stream>>>(
        Wq, Wk, Wv, Wo, Wt, Woth, Wotl);

    gemm_qkv_kernel<<<dim3(3 * Dd / 128, Mm / 128), 256, 0, stream>>>(
        xb, Wt, bq, bk, bv, QKV);

    attn_mfma_kernel<<<(Ss / 128) * (Bb * Hh), 512, 0, stream>>>(
        QKV, QKV + per, QKV + 2 * per, valid, OhB, OlB);

    gemm_final_kernel<<<dim3(Dd / 64, Mm / 128), 256, 0, stream>>>(
        OhB, OlB, Woth, Wotl, bo, (float*)d_out);
}